// Round 5
// baseline (198.330 us; speedup 1.0000x reference)
//
#include <hip/hip_runtime.h>
#include <hip/hip_bf16.h>
#include <math.h>

#define H_IMG 128
#define W_IMG 128
#define N_G   1024
#define F_DIM 512
#define O_DIM 512
#define PIX   (H_IMG*W_IMG)        // 16384
#define FEAT_OFF 49152             // 3*PIX
#define RAD_OFF  (49152 + 512*16384)
#define MAXG  192                  // per-tile survivor cap (mean ~70, validated r2/r3)

// ---------------------------------------------------------------------------
// Kernel 1: per-gaussian preprocessing (projection, conic, radii)
// ---------------------------------------------------------------------------
__global__ void prep_kernel(const float* __restrict__ means,
                            const float* __restrict__ opac,
                            const float* __restrict__ scales,
                            const float* __restrict__ rots,
                            const float* __restrict__ view,
                            const float* __restrict__ proj,
                            float* __restrict__ params8,
                            float* __restrict__ radii_out)
{
    int n = blockIdx.x * blockDim.x + threadIdx.x;
    if (n >= N_G) return;

    float x = means[3*n], y = means[3*n+1], z = means[3*n+2];
    float pv0 = x*view[0] + y*view[4] + z*view[8]  + view[12];
    float pv1 = x*view[1] + y*view[5] + z*view[9]  + view[13];
    float pv2 = x*view[2] + y*view[6] + z*view[10] + view[14];
    float ph0 = x*proj[0] + y*proj[4] + z*proj[8]  + proj[12];
    float ph1 = x*proj[1] + y*proj[5] + z*proj[9]  + proj[13];
    float phw = x*proj[3] + y*proj[7] + z*proj[11] + proj[15];
    float denom = phw + 1e-7f;
    float pp0 = ph0/denom, pp1 = ph1/denom;
    float depth = pv2;

    float qr=rots[4*n], qx=rots[4*n+1], qy=rots[4*n+2], qz=rots[4*n+3];
    float qn = sqrtf(qr*qr+qx*qx+qy*qy+qz*qz);
    qr/=qn; qx/=qn; qy/=qn; qz/=qn;
    float R00=1.f-2.f*(qy*qy+qz*qz), R01=2.f*(qx*qy-qr*qz), R02=2.f*(qx*qz+qr*qy);
    float R10=2.f*(qx*qy+qr*qz), R11=1.f-2.f*(qx*qx+qz*qz), R12=2.f*(qy*qz-qr*qx);
    float R20=2.f*(qx*qz-qr*qy), R21=2.f*(qy*qz+qr*qx), R22=1.f-2.f*(qx*qx+qy*qy);
    float s0=scales[3*n], s1=scales[3*n+1], s2=scales[3*n+2];
    float M00=R00*s0, M01=R01*s1, M02=R02*s2;
    float M10=R10*s0, M11=R11*s1, M12=R12*s2;
    float M20=R20*s0, M21=R21*s1, M22=R22*s2;
    float c00=M00*M00+M01*M01+M02*M02;
    float c01=M00*M10+M01*M11+M02*M12;
    float c02=M00*M20+M01*M21+M02*M22;
    float c11=M10*M10+M11*M11+M12*M12;
    float c12=M10*M20+M11*M21+M12*M22;
    float c22=M20*M20+M21*M21+M22*M22;

    const float fx=128.f, fy=128.f;
    float tz = pv2;
    float txz = fminf(fmaxf(pv0/tz, -0.65f), 0.65f) * tz;
    float tyz = fminf(fmaxf(pv1/tz, -0.65f), 0.65f) * tz;
    float J00 = fx/tz,  J02 = -fx*txz/(tz*tz);
    float J11 = fy/tz,  J12 = -fy*tyz/(tz*tz);
    float T00=J00*view[0] + J02*view[2];
    float T01=J00*view[4] + J02*view[6];
    float T02=J00*view[8] + J02*view[10];
    float T10=J11*view[1] + J12*view[2];
    float T11=J11*view[5] + J12*view[6];
    float T12=J11*view[9] + J12*view[10];
    float u0 = T00*c00 + T01*c01 + T02*c02;
    float u1 = T00*c01 + T01*c11 + T02*c12;
    float u2 = T00*c02 + T01*c12 + T02*c22;
    float v0 = T10*c00 + T11*c01 + T12*c02;
    float v1 = T10*c01 + T11*c11 + T12*c12;
    float v2 = T10*c02 + T11*c12 + T12*c22;
    float a00 = u0*T00 + u1*T01 + u2*T02 + 0.3f;
    float a01 = u0*T10 + u1*T11 + u2*T12;
    float a11 = v0*T10 + v1*T11 + v2*T12 + 0.3f;

    float det = a00*a11 - a01*a01;
    float dsafe = (det==0.f) ? 1.f : det;
    float inv = 1.f/dsafe;
    float con0 =  a11*inv, con1 = -a01*inv, con2 = a00*inv;
    float mid = 0.5f*(a00+a11);
    float lam1 = mid + sqrtf(fmaxf(0.1f, mid*mid - det));
    int irad = (int)ceilf(3.f*sqrtf(lam1));
    float pxc = ((pp0+1.f)*128.f - 1.f)*0.5f;
    float pyc = ((pp1+1.f)*128.f - 1.f)*0.5f;
    bool valid = (depth > 0.2f) && (det != 0.f);

    radii_out[n] = valid ? (float)irad : 0.f;
    float* p = params8 + 8*n;
    p[0]=pxc; p[1]=pyc; p[2]=con0; p[3]=con1; p[4]=con2;
    p[5]=opac[n]; p[6]=depth; p[7]= valid ? 1.f : 0.f;
}

// ---------------------------------------------------------------------------
// Kernel 2: rank sort (stable argsort by depth)
// ---------------------------------------------------------------------------
__global__ void rank_kernel(const float* __restrict__ params8, int* __restrict__ order)
{
    __shared__ float d[N_G];
    int t = threadIdx.x;
    for (int i = t; i < N_G; i += 256) d[i] = params8[8*i+6];
    __syncthreads();
    int n = blockIdx.x*256 + t;
    float dn = d[n];
    int r = 0;
    for (int m = 0; m < N_G; ++m) {
        float dm = d[m];
        r += (dm < dn) || (dm == dn && m < n);
    }
    order[r] = n;
}

// ---------------------------------------------------------------------------
// Kernel 3: pack params/colors into sorted order
// ---------------------------------------------------------------------------
__global__ void pack_kernel(const float* __restrict__ params8,
                            const float* __restrict__ colors,
                            const int* __restrict__ order,
                            float* __restrict__ psort, float* __restrict__ csort)
{
    int k = blockIdx.x*256 + threadIdx.x;
    if (k >= N_G) return;
    int n = order[k];
    #pragma unroll
    for (int j = 0; j < 8; ++j) psort[8*k+j] = params8[8*n+j];
    csort[4*k+0] = colors[3*n+0];
    csort[4*k+1] = colors[3*n+1];
    csort[4*k+2] = colors[3*n+2];
    csort[4*k+3] = 0.f;
}

// ---------------------------------------------------------------------------
// Kernel 4a: Wt[k][o] = conv_w[o][k]   (512x512 transpose)
// ---------------------------------------------------------------------------
__global__ __launch_bounds__(256) void transposeW_kernel(const float* __restrict__ in,
                                                         float* __restrict__ outT)
{
    __shared__ float t[32][33];
    int k0 = blockIdx.x*32, o0 = blockIdx.y*32;
    int tx = threadIdx.x, ty = threadIdx.y;   // 32 x 8
    #pragma unroll
    for (int j = 0; j < 32; j += 8) t[ty+j][tx] = in[(size_t)(o0+ty+j)*F_DIM + k0+tx];
    __syncthreads();
    #pragma unroll
    for (int j = 0; j < 32; j += 8) outT[(size_t)(k0+ty+j)*O_DIM + o0+tx] = t[tx][ty+j];
}

// ---------------------------------------------------------------------------
// Kernel 4b: St[k][m] = S[order[m]][k]  (gathered 1024x512 -> 512x1024)
// ---------------------------------------------------------------------------
__global__ __launch_bounds__(256) void transposeS_kernel(const float* __restrict__ S,
                                                         const int* __restrict__ order,
                                                         float* __restrict__ St)
{
    __shared__ float t[32][33];
    int k0 = blockIdx.x*32, m0 = blockIdx.y*32;
    int tx = threadIdx.x, ty = threadIdx.y;   // 32 x 8
    #pragma unroll
    for (int j = 0; j < 32; j += 8) {
        int src = order[m0+ty+j];
        t[ty+j][tx] = S[(size_t)src*F_DIM + k0+tx];
    }
    __syncthreads();
    #pragma unroll
    for (int j = 0; j < 32; j += 8) St[(size_t)(k0+ty+j)*N_G + m0+tx] = t[tx][ty+j];
}

// ---------------------------------------------------------------------------
// Kernel 4c: Gv[m][o] = sum_k St[k][m] * Wt[k][o]
//   1 wave per block; lane = o; 16 m-rows per wave; A-slice via uniform
//   (scalar) loads, B coalesced per-lane; no LDS in inner loop.
// ---------------------------------------------------------------------------
__global__ __launch_bounds__(64) void gemmG_kernel(const float* __restrict__ Wt,
                                                   const float* __restrict__ St,
                                                   float* __restrict__ Gv)
{
    const int lane = threadIdx.x;
    const int o    = blockIdx.x*64 + lane;    // 8 o-groups
    const int m0   = blockIdx.y*16;           // 64 m-groups

    float acc[16];
    #pragma unroll
    for (int i = 0; i < 16; ++i) acc[i] = 0.f;

    #pragma unroll 4
    for (int k = 0; k < F_DIM; ++k) {
        float wv = Wt[(size_t)k*O_DIM + o];
        const float4* sp = reinterpret_cast<const float4*>(St + (size_t)k*N_G + m0);
        float4 s0 = sp[0], s1 = sp[1], s2 = sp[2], s3 = sp[3];
        acc[0]  += s0.x*wv; acc[1]  += s0.y*wv; acc[2]  += s0.z*wv; acc[3]  += s0.w*wv;
        acc[4]  += s1.x*wv; acc[5]  += s1.y*wv; acc[6]  += s1.z*wv; acc[7]  += s1.w*wv;
        acc[8]  += s2.x*wv; acc[9]  += s2.y*wv; acc[10] += s2.z*wv; acc[11] += s2.w*wv;
        acc[12] += s3.x*wv; acc[13] += s3.y*wv; acc[14] += s3.z*wv; acc[15] += s3.w*wv;
    }
    #pragma unroll
    for (int i = 0; i < 16; ++i) Gv[(size_t)(m0+i)*O_DIM + o] = acc[i];
}

// ---------------------------------------------------------------------------
// Kernel 5: alpha/compositing. One block per 64-px strip, 16 waves = 16
// independent 64-gaussian chunks. Emits compacted, depth-ordered, FINAL
// (cross-chunk scaled) bf16 weight rows + color image.
// ---------------------------------------------------------------------------
__global__ __launch_bounds__(1024) void alpha_kernel(
    const float* __restrict__ psort, const float* __restrict__ csort,
    const float* __restrict__ bg,
    __hip_bfloat16* __restrict__ wbuf, int* __restrict__ idxl,
    int* __restrict__ cnttot, float* __restrict__ out)
{
    __shared__ float pg[N_G][8];
    __shared__ float cs[N_G][4];
    __shared__ float Pl[16][64];
    __shared__ float colbuf[16][64][4];
    __shared__ float Tfl[64];
    __shared__ int   cntl_s[16];

    const int t    = threadIdx.x;
    const int c    = t >> 6;        // chunk / wave
    const int lane = t & 63;        // pixel in strip
    const int tile = blockIdx.x;
    const int hrow = tile >> 1;
    const int w0   = (tile & 1) * 64;

    {
        float4* pgv = reinterpret_cast<float4*>(&pg[0][0]);
        const float4* ps4 = reinterpret_cast<const float4*>(psort);
        pgv[t]        = ps4[t];
        pgv[t + 1024] = ps4[t + 1024];
        float4* csv = reinterpret_cast<float4*>(&cs[0][0]);
        csv[t] = reinterpret_cast<const float4*>(csort)[t];
    }
    __syncthreads();

    const float gx = (float)(w0 + lane);
    const float gy = (float)hrow;

    // pass 1: per-chunk transmittance + survivor count
    float pref = 1.f;
    int cnt = 0;
    for (int j = 0; j < 64; ++j) {
        int g = c*64 + j;
        float4 A = *reinterpret_cast<const float4*>(&pg[g][0]);
        float4 B = *reinterpret_cast<const float4*>(&pg[g][4]);
        float dx = A.x - gx, dy = A.y - gy;
        float pw = -0.5f*(A.z*dx*dx + B.x*dy*dy) - A.w*dx*dy;
        float al = fminf(0.99f, B.y*__expf(pw));
        bool keep = (pw <= 0.f) && (al >= (1.f/255.f)) && (B.w > 0.5f);
        float a = keep ? al : 0.f;
        float w = pref * a;
        pref *= 1.f - a;
        cnt += (__ballot(w > 1e-12f) != 0ull) ? 1 : 0;
    }
    Pl[c][lane] = pref;
    if (lane == 0) cntl_s[c] = cnt;
    __syncthreads();

    int base = 0;
    float cp = 1.f;
    for (int cc = 0; cc < c; ++cc) {
        base += cntl_s[cc];
        cp *= Pl[cc][lane];
    }
    if (c == 15) {
        Tfl[lane] = cp * Pl[15][lane];
        if (lane == 0) {
            int tot = base + cntl_s[15];
            cnttot[tile] = (tot < MAXG) ? tot : MAXG;
        }
    }

    // pass 2: recompute alphas, write final bf16 weights + color
    float pref2 = 1.f;
    int slot = base;
    float col0 = 0.f, col1 = 0.f, col2 = 0.f;
    for (int j = 0; j < 64; ++j) {
        int g = c*64 + j;
        float4 A = *reinterpret_cast<const float4*>(&pg[g][0]);
        float4 B = *reinterpret_cast<const float4*>(&pg[g][4]);
        float dx = A.x - gx, dy = A.y - gy;
        float pw = -0.5f*(A.z*dx*dx + B.x*dy*dy) - A.w*dx*dy;
        float al = fminf(0.99f, B.y*__expf(pw));
        bool keep = (pw <= 0.f) && (al >= (1.f/255.f)) && (B.w > 0.5f);
        float a = keep ? al : 0.f;
        float w = pref2 * a;
        pref2 *= 1.f - a;
        if (__ballot(w > 1e-12f) != 0ull) {
            float wfin = w * cp;
            if (slot < MAXG) {
                wbuf[((size_t)tile*MAXG + slot)*64 + lane] = __float2bfloat16(wfin);
                if (lane == 0) idxl[tile*MAXG + slot] = g;
            }
            float4 cv = *reinterpret_cast<const float4*>(&cs[g][0]);
            col0 += wfin*cv.x; col1 += wfin*cv.y; col2 += wfin*cv.z;
            ++slot;
        }
    }

    colbuf[c][lane][0] = col0; colbuf[c][lane][1] = col1; colbuf[c][lane][2] = col2;
    __syncthreads();

    if (t < 64) {
        float r = 0.f, g = 0.f, b = 0.f;
        #pragma unroll
        for (int k = 0; k < 16; ++k) {
            r += colbuf[k][t][0]; g += colbuf[k][t][1]; b += colbuf[k][t][2];
        }
        float Tf = Tfl[t];
        int pix = hrow*W_IMG + w0 + t;
        out[0*PIX + pix] = r + Tf*bg[0];
        out[1*PIX + pix] = g + Tf*bg[1];
        out[2*PIX + pix] = b + Tf*bg[2];
    }
}

// ---------------------------------------------------------------------------
// Kernel 6: per-tile feature GEMM, software-pipelined 2-deep.
//   grid (4, 256), 256 threads: px = t&63 (lane), oc = t>>6, 32 outputs/thread.
//   NOTE: macro parameter must NOT be named `w` (clashes with float4 .w).
// ---------------------------------------------------------------------------
#define LOADG(r0,r1,r2,r3,r4,r5,r6,r7, gp) \
    r0 = (gp)[0]; r1 = (gp)[1]; r2 = (gp)[2]; r3 = (gp)[3]; \
    r4 = (gp)[4]; r5 = (gp)[5]; r6 = (gp)[6]; r7 = (gp)[7];

#define FMAS(wm, r0,r1,r2,r3,r4,r5,r6,r7) \
    acc[0]+=(wm)*r0.x; acc[1]+=(wm)*r0.y; acc[2]+=(wm)*r0.z; acc[3]+=(wm)*r0.w; \
    acc[4]+=(wm)*r1.x; acc[5]+=(wm)*r1.y; acc[6]+=(wm)*r1.z; acc[7]+=(wm)*r1.w; \
    acc[8]+=(wm)*r2.x; acc[9]+=(wm)*r2.y; acc[10]+=(wm)*r2.z; acc[11]+=(wm)*r2.w; \
    acc[12]+=(wm)*r3.x; acc[13]+=(wm)*r3.y; acc[14]+=(wm)*r3.z; acc[15]+=(wm)*r3.w; \
    acc[16]+=(wm)*r4.x; acc[17]+=(wm)*r4.y; acc[18]+=(wm)*r4.z; acc[19]+=(wm)*r4.w; \
    acc[20]+=(wm)*r5.x; acc[21]+=(wm)*r5.y; acc[22]+=(wm)*r5.z; acc[23]+=(wm)*r5.w; \
    acc[24]+=(wm)*r6.x; acc[25]+=(wm)*r6.y; acc[26]+=(wm)*r6.z; acc[27]+=(wm)*r6.w; \
    acc[28]+=(wm)*r7.x; acc[29]+=(wm)*r7.y; acc[30]+=(wm)*r7.z; acc[31]+=(wm)*r7.w;

__global__ __launch_bounds__(256) void featgemm_kernel(
    const __hip_bfloat16* __restrict__ wbuf, const int* __restrict__ idxl,
    const int* __restrict__ cnttot, const float* __restrict__ Gv,
    const float* __restrict__ conv_b, float* __restrict__ out)
{
    const int t    = threadIdx.x;
    const int px   = t & 63;
    const int oc   = t >> 6;                  // 0..3
    const int tile = blockIdx.y;
    const int o0   = blockIdx.x*128 + oc*32;

    const int cnt = cnttot[tile];
    const __hip_bfloat16* wb = wbuf + (size_t)tile*MAXG*64;
    const int* ib = idxl + tile*MAXG;

    float acc[32];
    #pragma unroll
    for (int q = 0; q < 32; ++q) acc[q] = 0.f;

    if (cnt > 0) {
        float4 a0,a1,a2,a3,a4,a5,a6,a7;
        float4 b0,b1,b2,b3,b4,b5,b6,b7;
        float wa, wbv;

        int g = ib[0];
        const float4* gp = reinterpret_cast<const float4*>(Gv + (size_t)g*O_DIM + o0);
        LOADG(a0,a1,a2,a3,a4,a5,a6,a7, gp);
        wa = __bfloat162float(wb[px]);

        int s = 0;
        while (true) {
            int s1 = s + 1;
            if (s1 < cnt) {
                int g1 = ib[s1];
                const float4* gq = reinterpret_cast<const float4*>(Gv + (size_t)g1*O_DIM + o0);
                LOADG(b0,b1,b2,b3,b4,b5,b6,b7, gq);
                wbv = __bfloat162float(wb[s1*64 + px]);
            }
            FMAS(wa, a0,a1,a2,a3,a4,a5,a6,a7);
            if (s1 >= cnt) break;

            int s2 = s1 + 1;
            if (s2 < cnt) {
                int g2 = ib[s2];
                const float4* gq = reinterpret_cast<const float4*>(Gv + (size_t)g2*O_DIM + o0);
                LOADG(a0,a1,a2,a3,a4,a5,a6,a7, gq);
                wa = __bfloat162float(wb[s2*64 + px]);
            }
            FMAS(wbv, b0,b1,b2,b3,b4,b5,b6,b7);
            if (s2 >= cnt) break;
            s = s2;
        }
    }

    const int pix = (tile >> 1)*W_IMG + (tile & 1)*64 + px;
    #pragma unroll
    for (int q = 0; q < 32; ++q) {
        out[FEAT_OFF + (size_t)(o0+q)*PIX + pix] = acc[q] + conv_b[o0+q];
    }
}

// ---------------------------------------------------------------------------
extern "C" void kernel_launch(void* const* d_in, const int* in_sizes, int n_in,
                              void* d_out, int out_size, void* d_ws, size_t ws_size,
                              hipStream_t stream)
{
    const float* means  = (const float*)d_in[0];
    const float* opac   = (const float*)d_in[2];
    const float* colors = (const float*)d_in[3];
    const float* sem    = (const float*)d_in[4];
    const float* scales = (const float*)d_in[5];
    const float* rots   = (const float*)d_in[6];
    const float* view   = (const float*)d_in[7];
    const float* proj   = (const float*)d_in[8];
    const float* bg     = (const float*)d_in[9];
    const float* conv_w = (const float*)d_in[11];
    const float* conv_b = (const float*)d_in[12];
    float* out = (float*)d_out;

    float* wsf     = (float*)d_ws;
    float* params8 = wsf;                    // 8192
    float* psort   = wsf + 8192;             // 8192
    float* csort   = wsf + 16384;            // 4096
    int*   order   = (int*)(wsf + 20480);    // 1024 ints
    int*   cnttot  = (int*)(wsf + 21504);    // 256 ints
    float* Wt      = wsf + 24576;            // 512*512 = 262144
    float* St      = wsf + 286720;           // 512*1024 = 524288
    float* Gv      = wsf + 811008;           // 1024*512 = 524288
    int*   idxl    = (int*)(wsf + 1335296);  // 256*192 ints
    __hip_bfloat16* wbuf = (__hip_bfloat16*)(wsf + 1384448); // 256*192*64 bf16

    float* radii_out = out + RAD_OFF;

    prep_kernel<<<4, 256, 0, stream>>>(means, opac, scales, rots, view, proj,
                                       params8, radii_out);
    transposeW_kernel<<<dim3(16,16), dim3(32,8), 0, stream>>>(conv_w, Wt);
    rank_kernel<<<4, 256, 0, stream>>>(params8, order);
    pack_kernel<<<4, 256, 0, stream>>>(params8, colors, order, psort, csort);
    transposeS_kernel<<<dim3(16,32), dim3(32,8), 0, stream>>>(sem, order, St);
    gemmG_kernel<<<dim3(8,64), 64, 0, stream>>>(Wt, St, Gv);
    alpha_kernel<<<256, 1024, 0, stream>>>(psort, csort, bg, wbuf, idxl, cnttot, out);
    featgemm_kernel<<<dim3(4,256), 256, 0, stream>>>(wbuf, idxl, cnttot, Gv, conv_b, out);
}

// Round 6
// 180.257 us; speedup vs baseline: 1.1003x; 1.1003x over previous
//
#include <hip/hip_runtime.h>
#include <hip/hip_bf16.h>
#include <math.h>

#define H_IMG 128
#define W_IMG 128
#define N_G   1024
#define F_DIM 512
#define O_DIM 512
#define PIX   (H_IMG*W_IMG)        // 16384
#define FEAT_OFF 49152             // 3*PIX
#define RAD_OFF  (49152 + 512*16384)
#define MAXG  192                  // per-tile survivor cap (mean ~70, validated r2/r3)

// ---------------------------------------------------------------------------
// Kernel 1: per-gaussian preprocessing (projection, conic, radii)
// ---------------------------------------------------------------------------
__global__ void prep_kernel(const float* __restrict__ means,
                            const float* __restrict__ opac,
                            const float* __restrict__ scales,
                            const float* __restrict__ rots,
                            const float* __restrict__ view,
                            const float* __restrict__ proj,
                            float* __restrict__ params8,
                            float* __restrict__ radii_out)
{
    int n = blockIdx.x * blockDim.x + threadIdx.x;
    if (n >= N_G) return;

    float x = means[3*n], y = means[3*n+1], z = means[3*n+2];
    float pv0 = x*view[0] + y*view[4] + z*view[8]  + view[12];
    float pv1 = x*view[1] + y*view[5] + z*view[9]  + view[13];
    float pv2 = x*view[2] + y*view[6] + z*view[10] + view[14];
    float ph0 = x*proj[0] + y*proj[4] + z*proj[8]  + proj[12];
    float ph1 = x*proj[1] + y*proj[5] + z*proj[9]  + proj[13];
    float phw = x*proj[3] + y*proj[7] + z*proj[11] + proj[15];
    float denom = phw + 1e-7f;
    float pp0 = ph0/denom, pp1 = ph1/denom;
    float depth = pv2;

    float qr=rots[4*n], qx=rots[4*n+1], qy=rots[4*n+2], qz=rots[4*n+3];
    float qn = sqrtf(qr*qr+qx*qx+qy*qy+qz*qz);
    qr/=qn; qx/=qn; qy/=qn; qz/=qn;
    float R00=1.f-2.f*(qy*qy+qz*qz), R01=2.f*(qx*qy-qr*qz), R02=2.f*(qx*qz+qr*qy);
    float R10=2.f*(qx*qy+qr*qz), R11=1.f-2.f*(qx*qx+qz*qz), R12=2.f*(qy*qz-qr*qx);
    float R20=2.f*(qx*qz-qr*qy), R21=2.f*(qy*qz+qr*qx), R22=1.f-2.f*(qx*qx+qy*qy);
    float s0=scales[3*n], s1=scales[3*n+1], s2=scales[3*n+2];
    float M00=R00*s0, M01=R01*s1, M02=R02*s2;
    float M10=R10*s0, M11=R11*s1, M12=R12*s2;
    float M20=R20*s0, M21=R21*s1, M22=R22*s2;
    float c00=M00*M00+M01*M01+M02*M02;
    float c01=M00*M10+M01*M11+M02*M12;
    float c02=M00*M20+M01*M21+M02*M22;
    float c11=M10*M10+M11*M11+M12*M12;
    float c12=M10*M20+M11*M21+M12*M22;
    float c22=M20*M20+M21*M21+M22*M22;

    const float fx=128.f, fy=128.f;
    float tz = pv2;
    float txz = fminf(fmaxf(pv0/tz, -0.65f), 0.65f) * tz;
    float tyz = fminf(fmaxf(pv1/tz, -0.65f), 0.65f) * tz;
    float J00 = fx/tz,  J02 = -fx*txz/(tz*tz);
    float J11 = fy/tz,  J12 = -fy*tyz/(tz*tz);
    float T00=J00*view[0] + J02*view[2];
    float T01=J00*view[4] + J02*view[6];
    float T02=J00*view[8] + J02*view[10];
    float T10=J11*view[1] + J12*view[2];
    float T11=J11*view[5] + J12*view[6];
    float T12=J11*view[9] + J12*view[10];
    float u0 = T00*c00 + T01*c01 + T02*c02;
    float u1 = T00*c01 + T01*c11 + T02*c12;
    float u2 = T00*c02 + T01*c12 + T02*c22;
    float v0 = T10*c00 + T11*c01 + T12*c02;
    float v1 = T10*c01 + T11*c11 + T12*c12;
    float v2 = T10*c02 + T11*c12 + T12*c22;
    float a00 = u0*T00 + u1*T01 + u2*T02 + 0.3f;
    float a01 = u0*T10 + u1*T11 + u2*T12;
    float a11 = v0*T10 + v1*T11 + v2*T12 + 0.3f;

    float det = a00*a11 - a01*a01;
    float dsafe = (det==0.f) ? 1.f : det;
    float inv = 1.f/dsafe;
    float con0 =  a11*inv, con1 = -a01*inv, con2 = a00*inv;
    float mid = 0.5f*(a00+a11);
    float lam1 = mid + sqrtf(fmaxf(0.1f, mid*mid - det));
    int irad = (int)ceilf(3.f*sqrtf(lam1));
    float pxc = ((pp0+1.f)*128.f - 1.f)*0.5f;
    float pyc = ((pp1+1.f)*128.f - 1.f)*0.5f;
    bool valid = (depth > 0.2f) && (det != 0.f);

    radii_out[n] = valid ? (float)irad : 0.f;
    float* p = params8 + 8*n;
    p[0]=pxc; p[1]=pyc; p[2]=con0; p[3]=con1; p[4]=con2;
    p[5]=opac[n]; p[6]=depth; p[7]= valid ? 1.f : 0.f;
}

// ---------------------------------------------------------------------------
// Kernel 2: rank sort (stable argsort by depth)
// ---------------------------------------------------------------------------
__global__ void rank_kernel(const float* __restrict__ params8, int* __restrict__ order)
{
    __shared__ float d[N_G];
    int t = threadIdx.x;
    for (int i = t; i < N_G; i += 256) d[i] = params8[8*i+6];
    __syncthreads();
    int n = blockIdx.x*256 + t;
    float dn = d[n];
    int r = 0;
    for (int m = 0; m < N_G; ++m) {
        float dm = d[m];
        r += (dm < dn) || (dm == dn && m < n);
    }
    order[r] = n;
}

// ---------------------------------------------------------------------------
// Kernel 3: pack params/colors into sorted order
// ---------------------------------------------------------------------------
__global__ void pack_kernel(const float* __restrict__ params8,
                            const float* __restrict__ colors,
                            const int* __restrict__ order,
                            float* __restrict__ psort, float* __restrict__ csort)
{
    int k = blockIdx.x*256 + threadIdx.x;
    if (k >= N_G) return;
    int n = order[k];
    #pragma unroll
    for (int j = 0; j < 8; ++j) psort[8*k+j] = params8[8*n+j];
    csort[4*k+0] = colors[3*n+0];
    csort[4*k+1] = colors[3*n+1];
    csort[4*k+2] = colors[3*n+2];
    csort[4*k+3] = 0.f;
}

// ---------------------------------------------------------------------------
// Kernel 4a: Wt[k][o] = conv_w[o][k]   (512x512 transpose)
// ---------------------------------------------------------------------------
__global__ __launch_bounds__(256) void transposeW_kernel(const float* __restrict__ in,
                                                         float* __restrict__ outT)
{
    __shared__ float t[32][33];
    int k0 = blockIdx.x*32, o0 = blockIdx.y*32;
    int tx = threadIdx.x, ty = threadIdx.y;   // 32 x 8
    #pragma unroll
    for (int j = 0; j < 32; j += 8) t[ty+j][tx] = in[(size_t)(o0+ty+j)*F_DIM + k0+tx];
    __syncthreads();
    #pragma unroll
    for (int j = 0; j < 32; j += 8) outT[(size_t)(k0+ty+j)*O_DIM + o0+tx] = t[tx][ty+j];
}

// ---------------------------------------------------------------------------
// Kernel 4b: St[k][m] = S[order[m]][k]  (gathered 1024x512 -> 512x1024)
// ---------------------------------------------------------------------------
__global__ __launch_bounds__(256) void transposeS_kernel(const float* __restrict__ S,
                                                         const int* __restrict__ order,
                                                         float* __restrict__ St)
{
    __shared__ float t[32][33];
    int k0 = blockIdx.x*32, m0 = blockIdx.y*32;
    int tx = threadIdx.x, ty = threadIdx.y;   // 32 x 8
    #pragma unroll
    for (int j = 0; j < 32; j += 8) {
        int src = order[m0+ty+j];
        t[ty+j][tx] = S[(size_t)src*F_DIM + k0+tx];
    }
    __syncthreads();
    #pragma unroll
    for (int j = 0; j < 32; j += 8) St[(size_t)(k0+ty+j)*N_G + m0+tx] = t[tx][ty+j];
}

// ---------------------------------------------------------------------------
// Kernel 4c: Gv[m][o] = sum_k St[k][m] * Wt[k][o]
//   grid (8 o-groups, 64 m-groups), 256 threads = 4 waves.
//   K split across the 4 waves (128 each) + LDS cross-wave reduction.
// ---------------------------------------------------------------------------
__global__ __launch_bounds__(256) void gemmG_kernel(const float* __restrict__ Wt,
                                                    const float* __restrict__ St,
                                                    float* __restrict__ Gv)
{
    __shared__ float red[3][16][64];          // partials from waves 1..3 (12 KB)

    const int t    = threadIdx.x;
    const int lane = t & 63;
    const int wv   = t >> 6;                  // 0..3 -> K chunk
    const int o    = blockIdx.x*64 + lane;
    const int m0   = blockIdx.y*16;

    float acc[16];
    #pragma unroll
    for (int i = 0; i < 16; ++i) acc[i] = 0.f;

    const int kbeg = wv*128;
    #pragma unroll 4
    for (int k = kbeg; k < kbeg + 128; ++k) {
        float wvv = Wt[(size_t)k*O_DIM + o];
        const float4* sp = reinterpret_cast<const float4*>(St + (size_t)k*N_G + m0);
        float4 s0 = sp[0], s1 = sp[1], s2 = sp[2], s3 = sp[3];
        acc[0]  += s0.x*wvv; acc[1]  += s0.y*wvv; acc[2]  += s0.z*wvv; acc[3]  += s0.w*wvv;
        acc[4]  += s1.x*wvv; acc[5]  += s1.y*wvv; acc[6]  += s1.z*wvv; acc[7]  += s1.w*wvv;
        acc[8]  += s2.x*wvv; acc[9]  += s2.y*wvv; acc[10] += s2.z*wvv; acc[11] += s2.w*wvv;
        acc[12] += s3.x*wvv; acc[13] += s3.y*wvv; acc[14] += s3.z*wvv; acc[15] += s3.w*wvv;
    }

    if (wv > 0) {
        #pragma unroll
        for (int i = 0; i < 16; ++i) red[wv-1][i][lane] = acc[i];
    }
    __syncthreads();
    if (wv == 0) {
        #pragma unroll
        for (int i = 0; i < 16; ++i) {
            float v = acc[i] + red[0][i][lane] + red[1][i][lane] + red[2][i][lane];
            Gv[(size_t)(m0+i)*O_DIM + o] = v;
        }
    }
}

// ---------------------------------------------------------------------------
// Kernel 5: alpha/compositing. One block per 64-px strip, 16 waves = 16
// independent 64-gaussian chunks. Emits compacted, depth-ordered, FINAL
// (cross-chunk scaled) bf16 weight rows + color image.
// ---------------------------------------------------------------------------
__global__ __launch_bounds__(1024) void alpha_kernel(
    const float* __restrict__ psort, const float* __restrict__ csort,
    const float* __restrict__ bg,
    __hip_bfloat16* __restrict__ wbuf, int* __restrict__ idxl,
    int* __restrict__ cnttot, float* __restrict__ out)
{
    __shared__ float pg[N_G][8];
    __shared__ float cs[N_G][4];
    __shared__ float Pl[16][64];
    __shared__ float colbuf[16][64][4];
    __shared__ float Tfl[64];
    __shared__ int   cntl_s[16];

    const int t    = threadIdx.x;
    const int c    = t >> 6;        // chunk / wave
    const int lane = t & 63;        // pixel in strip
    const int tile = blockIdx.x;
    const int hrow = tile >> 1;
    const int w0   = (tile & 1) * 64;

    {
        float4* pgv = reinterpret_cast<float4*>(&pg[0][0]);
        const float4* ps4 = reinterpret_cast<const float4*>(psort);
        pgv[t]        = ps4[t];
        pgv[t + 1024] = ps4[t + 1024];
        float4* csv = reinterpret_cast<float4*>(&cs[0][0]);
        csv[t] = reinterpret_cast<const float4*>(csort)[t];
    }
    __syncthreads();

    const float gx = (float)(w0 + lane);
    const float gy = (float)hrow;

    // pass 1: per-chunk transmittance + survivor count
    float pref = 1.f;
    int cnt = 0;
    for (int j = 0; j < 64; ++j) {
        int g = c*64 + j;
        float4 A = *reinterpret_cast<const float4*>(&pg[g][0]);
        float4 B = *reinterpret_cast<const float4*>(&pg[g][4]);
        float dx = A.x - gx, dy = A.y - gy;
        float pw = -0.5f*(A.z*dx*dx + B.x*dy*dy) - A.w*dx*dy;
        float al = fminf(0.99f, B.y*__expf(pw));
        bool keep = (pw <= 0.f) && (al >= (1.f/255.f)) && (B.w > 0.5f);
        float a = keep ? al : 0.f;
        float w = pref * a;
        pref *= 1.f - a;
        cnt += (__ballot(w > 1e-12f) != 0ull) ? 1 : 0;
    }
    Pl[c][lane] = pref;
    if (lane == 0) cntl_s[c] = cnt;
    __syncthreads();

    int base = 0;
    float cp = 1.f;
    for (int cc = 0; cc < c; ++cc) {
        base += cntl_s[cc];
        cp *= Pl[cc][lane];
    }
    if (c == 15) {
        Tfl[lane] = cp * Pl[15][lane];
        if (lane == 0) {
            int tot = base + cntl_s[15];
            cnttot[tile] = (tot < MAXG) ? tot : MAXG;
        }
    }

    // pass 2: recompute alphas, write final bf16 weights + color
    float pref2 = 1.f;
    int slot = base;
    float col0 = 0.f, col1 = 0.f, col2 = 0.f;
    for (int j = 0; j < 64; ++j) {
        int g = c*64 + j;
        float4 A = *reinterpret_cast<const float4*>(&pg[g][0]);
        float4 B = *reinterpret_cast<const float4*>(&pg[g][4]);
        float dx = A.x - gx, dy = A.y - gy;
        float pw = -0.5f*(A.z*dx*dx + B.x*dy*dy) - A.w*dx*dy;
        float al = fminf(0.99f, B.y*__expf(pw));
        bool keep = (pw <= 0.f) && (al >= (1.f/255.f)) && (B.w > 0.5f);
        float a = keep ? al : 0.f;
        float w = pref2 * a;
        pref2 *= 1.f - a;
        if (__ballot(w > 1e-12f) != 0ull) {
            float wfin = w * cp;
            if (slot < MAXG) {
                wbuf[((size_t)tile*MAXG + slot)*64 + lane] = __float2bfloat16(wfin);
                if (lane == 0) idxl[tile*MAXG + slot] = g;
            }
            float4 cv = *reinterpret_cast<const float4*>(&cs[g][0]);
            col0 += wfin*cv.x; col1 += wfin*cv.y; col2 += wfin*cv.z;
            ++slot;
        }
    }

    colbuf[c][lane][0] = col0; colbuf[c][lane][1] = col1; colbuf[c][lane][2] = col2;
    __syncthreads();

    if (t < 64) {
        float r = 0.f, g = 0.f, b = 0.f;
        #pragma unroll
        for (int k = 0; k < 16; ++k) {
            r += colbuf[k][t][0]; g += colbuf[k][t][1]; b += colbuf[k][t][2];
        }
        float Tf = Tfl[t];
        int pix = hrow*W_IMG + w0 + t;
        out[0*PIX + pix] = r + Tf*bg[0];
        out[1*PIX + pix] = g + Tf*bg[1];
        out[2*PIX + pix] = b + Tf*bg[2];
    }
}

// ---------------------------------------------------------------------------
// Kernel 6: per-tile feature GEMM.
//   grid (16 o-slices, 256 tiles) = 4096 blocks, 256 threads.
//   px = t&63, oc = t>>6, 8 outputs/thread. Survivor indices staged in LDS
//   (so the global-load chain is only the independent, batched G-row loads).
// ---------------------------------------------------------------------------
__global__ __launch_bounds__(256) void featgemm_kernel(
    const __hip_bfloat16* __restrict__ wbuf, const int* __restrict__ idxl,
    const int* __restrict__ cnttot, const float* __restrict__ Gv,
    const float* __restrict__ conv_b, float* __restrict__ out)
{
    __shared__ int ibs[MAXG];

    const int t    = threadIdx.x;
    const int px   = t & 63;
    const int oc   = t >> 6;                  // 0..3
    const int tile = blockIdx.y;
    const int o0   = blockIdx.x*32 + oc*8;

    const int cnt = cnttot[tile];
    if (t < MAXG) ibs[t] = idxl[tile*MAXG + t];
    __syncthreads();

    const __hip_bfloat16* wb = wbuf + (size_t)tile*MAXG*64 + px;

    float acc[8];
    #pragma unroll
    for (int q = 0; q < 8; ++q) acc[q] = 0.f;

    int s = 0;
    for (; s + 4 <= cnt; s += 4) {
        int g0 = ibs[s+0], g1 = ibs[s+1], g2 = ibs[s+2], g3 = ibs[s+3];
        float w0 = __bfloat162float(wb[(s+0)*64]);
        float w1 = __bfloat162float(wb[(s+1)*64]);
        float w2 = __bfloat162float(wb[(s+2)*64]);
        float w3 = __bfloat162float(wb[(s+3)*64]);
        const float4* p0 = reinterpret_cast<const float4*>(Gv + (size_t)g0*O_DIM + o0);
        const float4* p1 = reinterpret_cast<const float4*>(Gv + (size_t)g1*O_DIM + o0);
        const float4* p2 = reinterpret_cast<const float4*>(Gv + (size_t)g2*O_DIM + o0);
        const float4* p3 = reinterpret_cast<const float4*>(Gv + (size_t)g3*O_DIM + o0);
        float4 A0 = p0[0], A1 = p0[1];
        float4 B0 = p1[0], B1 = p1[1];
        float4 C0 = p2[0], C1 = p2[1];
        float4 D0 = p3[0], D1 = p3[1];
        acc[0] += w0*A0.x; acc[1] += w0*A0.y; acc[2] += w0*A0.z; acc[3] += w0*A0.w;
        acc[4] += w0*A1.x; acc[5] += w0*A1.y; acc[6] += w0*A1.z; acc[7] += w0*A1.w;
        acc[0] += w1*B0.x; acc[1] += w1*B0.y; acc[2] += w1*B0.z; acc[3] += w1*B0.w;
        acc[4] += w1*B1.x; acc[5] += w1*B1.y; acc[6] += w1*B1.z; acc[7] += w1*B1.w;
        acc[0] += w2*C0.x; acc[1] += w2*C0.y; acc[2] += w2*C0.z; acc[3] += w2*C0.w;
        acc[4] += w2*C1.x; acc[5] += w2*C1.y; acc[6] += w2*C1.z; acc[7] += w2*C1.w;
        acc[0] += w3*D0.x; acc[1] += w3*D0.y; acc[2] += w3*D0.z; acc[3] += w3*D0.w;
        acc[4] += w3*D1.x; acc[5] += w3*D1.y; acc[6] += w3*D1.z; acc[7] += w3*D1.w;
    }
    for (; s < cnt; ++s) {
        int g = ibs[s];
        float w = __bfloat162float(wb[s*64]);
        const float4* p = reinterpret_cast<const float4*>(Gv + (size_t)g*O_DIM + o0);
        float4 A0 = p[0], A1 = p[1];
        acc[0] += w*A0.x; acc[1] += w*A0.y; acc[2] += w*A0.z; acc[3] += w*A0.w;
        acc[4] += w*A1.x; acc[5] += w*A1.y; acc[6] += w*A1.z; acc[7] += w*A1.w;
    }

    const int pix = (tile >> 1)*W_IMG + (tile & 1)*64 + px;
    #pragma unroll
    for (int q = 0; q < 8; ++q) {
        out[FEAT_OFF + (size_t)(o0+q)*PIX + pix] = acc[q] + conv_b[o0+q];
    }
}

// ---------------------------------------------------------------------------
extern "C" void kernel_launch(void* const* d_in, const int* in_sizes, int n_in,
                              void* d_out, int out_size, void* d_ws, size_t ws_size,
                              hipStream_t stream)
{
    const float* means  = (const float*)d_in[0];
    const float* opac   = (const float*)d_in[2];
    const float* colors = (const float*)d_in[3];
    const float* sem    = (const float*)d_in[4];
    const float* scales = (const float*)d_in[5];
    const float* rots   = (const float*)d_in[6];
    const float* view   = (const float*)d_in[7];
    const float* proj   = (const float*)d_in[8];
    const float* bg     = (const float*)d_in[9];
    const float* conv_w = (const float*)d_in[11];
    const float* conv_b = (const float*)d_in[12];
    float* out = (float*)d_out;

    float* wsf     = (float*)d_ws;
    float* params8 = wsf;                    // 8192
    float* psort   = wsf + 8192;             // 8192
    float* csort   = wsf + 16384;            // 4096
    int*   order   = (int*)(wsf + 20480);    // 1024 ints
    int*   cnttot  = (int*)(wsf + 21504);    // 256 ints
    float* Wt      = wsf + 24576;            // 512*512 = 262144
    float* St      = wsf + 286720;           // 512*1024 = 524288
    float* Gv      = wsf + 811008;           // 1024*512 = 524288
    int*   idxl    = (int*)(wsf + 1335296);  // 256*192 ints
    __hip_bfloat16* wbuf = (__hip_bfloat16*)(wsf + 1384448); // 256*192*64 bf16

    float* radii_out = out + RAD_OFF;

    prep_kernel<<<4, 256, 0, stream>>>(means, opac, scales, rots, view, proj,
                                       params8, radii_out);
    transposeW_kernel<<<dim3(16,16), dim3(32,8), 0, stream>>>(conv_w, Wt);
    rank_kernel<<<4, 256, 0, stream>>>(params8, order);
    pack_kernel<<<4, 256, 0, stream>>>(params8, colors, order, psort, csort);
    transposeS_kernel<<<dim3(16,32), dim3(32,8), 0, stream>>>(sem, order, St);
    gemmG_kernel<<<dim3(8,64), 256, 0, stream>>>(Wt, St, Gv);
    alpha_kernel<<<256, 1024, 0, stream>>>(psort, csort, bg, wbuf, idxl, cnttot, out);
    featgemm_kernel<<<dim3(16,256), 256, 0, stream>>>(wbuf, idxl, cnttot, Gv, conv_b, out);
}

// Round 7
// 129.788 us; speedup vs baseline: 1.5281x; 1.3889x over previous
//
#include <hip/hip_runtime.h>
#include <hip/hip_bf16.h>
#include <math.h>

#define H_IMG 128
#define W_IMG 128
#define N_G   1024
#define F_DIM 512
#define O_DIM 512
#define PIX   (H_IMG*W_IMG)        // 16384
#define FEAT_OFF 49152             // 3*PIX
#define RAD_OFF  (49152 + 512*16384)
#define MAXG  192                  // per-tile survivor cap (mean ~70, validated r2/r3)

typedef __attribute__((ext_vector_type(8))) short bf16x8;
typedef __attribute__((ext_vector_type(4))) float f32x4;

// ---------------------------------------------------------------------------
// Kernel 1: per-gaussian preprocessing (projection, conic, radii)
// ---------------------------------------------------------------------------
__global__ void prep_kernel(const float* __restrict__ means,
                            const float* __restrict__ opac,
                            const float* __restrict__ scales,
                            const float* __restrict__ rots,
                            const float* __restrict__ view,
                            const float* __restrict__ proj,
                            float* __restrict__ params8,
                            float* __restrict__ radii_out)
{
    int n = blockIdx.x * blockDim.x + threadIdx.x;
    if (n >= N_G) return;

    float x = means[3*n], y = means[3*n+1], z = means[3*n+2];
    float pv0 = x*view[0] + y*view[4] + z*view[8]  + view[12];
    float pv1 = x*view[1] + y*view[5] + z*view[9]  + view[13];
    float pv2 = x*view[2] + y*view[6] + z*view[10] + view[14];
    float ph0 = x*proj[0] + y*proj[4] + z*proj[8]  + proj[12];
    float ph1 = x*proj[1] + y*proj[5] + z*proj[9]  + proj[13];
    float phw = x*proj[3] + y*proj[7] + z*proj[11] + proj[15];
    float denom = phw + 1e-7f;
    float pp0 = ph0/denom, pp1 = ph1/denom;
    float depth = pv2;

    float qr=rots[4*n], qx=rots[4*n+1], qy=rots[4*n+2], qz=rots[4*n+3];
    float qn = sqrtf(qr*qr+qx*qx+qy*qy+qz*qz);
    qr/=qn; qx/=qn; qy/=qn; qz/=qn;
    float R00=1.f-2.f*(qy*qy+qz*qz), R01=2.f*(qx*qy-qr*qz), R02=2.f*(qx*qz+qr*qy);
    float R10=2.f*(qx*qy+qr*qz), R11=1.f-2.f*(qx*qx+qz*qz), R12=2.f*(qy*qz-qr*qx);
    float R20=2.f*(qx*qz-qr*qy), R21=2.f*(qy*qz+qr*qx), R22=1.f-2.f*(qx*qx+qy*qy);
    float s0=scales[3*n], s1=scales[3*n+1], s2=scales[3*n+2];
    float M00=R00*s0, M01=R01*s1, M02=R02*s2;
    float M10=R10*s0, M11=R11*s1, M12=R12*s2;
    float M20=R20*s0, M21=R21*s1, M22=R22*s2;
    float c00=M00*M00+M01*M01+M02*M02;
    float c01=M00*M10+M01*M11+M02*M12;
    float c02=M00*M20+M01*M21+M02*M22;
    float c11=M10*M10+M11*M11+M12*M12;
    float c12=M10*M20+M11*M21+M12*M22;
    float c22=M20*M20+M21*M21+M22*M22;

    const float fx=128.f, fy=128.f;
    float tz = pv2;
    float txz = fminf(fmaxf(pv0/tz, -0.65f), 0.65f) * tz;
    float tyz = fminf(fmaxf(pv1/tz, -0.65f), 0.65f) * tz;
    float J00 = fx/tz,  J02 = -fx*txz/(tz*tz);
    float J11 = fy/tz,  J12 = -fy*tyz/(tz*tz);
    float T00=J00*view[0] + J02*view[2];
    float T01=J00*view[4] + J02*view[6];
    float T02=J00*view[8] + J02*view[10];
    float T10=J11*view[1] + J12*view[2];
    float T11=J11*view[5] + J12*view[6];
    float T12=J11*view[9] + J12*view[10];
    float u0 = T00*c00 + T01*c01 + T02*c02;
    float u1 = T00*c01 + T01*c11 + T02*c12;
    float u2 = T00*c02 + T01*c12 + T02*c22;
    float v0 = T10*c00 + T11*c01 + T12*c02;
    float v1 = T10*c01 + T11*c11 + T12*c12;
    float v2 = T10*c02 + T11*c12 + T12*c22;
    float a00 = u0*T00 + u1*T01 + u2*T02 + 0.3f;
    float a01 = u0*T10 + u1*T11 + u2*T12;
    float a11 = v0*T10 + v1*T11 + v2*T12 + 0.3f;

    float det = a00*a11 - a01*a01;
    float dsafe = (det==0.f) ? 1.f : det;
    float inv = 1.f/dsafe;
    float con0 =  a11*inv, con1 = -a01*inv, con2 = a00*inv;
    float mid = 0.5f*(a00+a11);
    float lam1 = mid + sqrtf(fmaxf(0.1f, mid*mid - det));
    int irad = (int)ceilf(3.f*sqrtf(lam1));
    float pxc = ((pp0+1.f)*128.f - 1.f)*0.5f;
    float pyc = ((pp1+1.f)*128.f - 1.f)*0.5f;
    bool valid = (depth > 0.2f) && (det != 0.f);

    radii_out[n] = valid ? (float)irad : 0.f;
    float* p = params8 + 8*n;
    p[0]=pxc; p[1]=pyc; p[2]=con0; p[3]=con1; p[4]=con2;
    p[5]=opac[n]; p[6]=depth; p[7]= valid ? 1.f : 0.f;
}

// ---------------------------------------------------------------------------
// Kernel 2: rank sort (stable argsort by depth)
// ---------------------------------------------------------------------------
__global__ void rank_kernel(const float* __restrict__ params8, int* __restrict__ order)
{
    __shared__ float d[N_G];
    int t = threadIdx.x;
    for (int i = t; i < N_G; i += 256) d[i] = params8[8*i+6];
    __syncthreads();
    int n = blockIdx.x*256 + t;
    float dn = d[n];
    int r = 0;
    for (int m = 0; m < N_G; ++m) {
        float dm = d[m];
        r += (dm < dn) || (dm == dn && m < n);
    }
    order[r] = n;
}

// ---------------------------------------------------------------------------
// Kernel 3: pack params/colors into sorted order
// ---------------------------------------------------------------------------
__global__ void pack_kernel(const float* __restrict__ params8,
                            const float* __restrict__ colors,
                            const int* __restrict__ order,
                            float* __restrict__ psort, float* __restrict__ csort)
{
    int k = blockIdx.x*256 + threadIdx.x;
    if (k >= N_G) return;
    int n = order[k];
    #pragma unroll
    for (int j = 0; j < 8; ++j) psort[8*k+j] = params8[8*n+j];
    csort[4*k+0] = colors[3*n+0];
    csort[4*k+1] = colors[3*n+1];
    csort[4*k+2] = colors[3*n+2];
    csort[4*k+3] = 0.f;
}

// ---------------------------------------------------------------------------
// Kernel 4a: Wt[k][o] = conv_w[o][k]   (512x512 transpose)
// ---------------------------------------------------------------------------
__global__ __launch_bounds__(256) void transposeW_kernel(const float* __restrict__ in,
                                                         float* __restrict__ outT)
{
    __shared__ float t[32][33];
    int k0 = blockIdx.x*32, o0 = blockIdx.y*32;
    int tx = threadIdx.x, ty = threadIdx.y;   // 32 x 8
    #pragma unroll
    for (int j = 0; j < 32; j += 8) t[ty+j][tx] = in[(size_t)(o0+ty+j)*F_DIM + k0+tx];
    __syncthreads();
    #pragma unroll
    for (int j = 0; j < 32; j += 8) outT[(size_t)(k0+ty+j)*O_DIM + o0+tx] = t[tx][ty+j];
}

// ---------------------------------------------------------------------------
// Kernel 4b: St[k][m] = S[order[m]][k]  (gathered 1024x512 -> 512x1024)
// ---------------------------------------------------------------------------
__global__ __launch_bounds__(256) void transposeS_kernel(const float* __restrict__ S,
                                                         const int* __restrict__ order,
                                                         float* __restrict__ St)
{
    __shared__ float t[32][33];
    int k0 = blockIdx.x*32, m0 = blockIdx.y*32;
    int tx = threadIdx.x, ty = threadIdx.y;   // 32 x 8
    #pragma unroll
    for (int j = 0; j < 32; j += 8) {
        int src = order[m0+ty+j];
        t[ty+j][tx] = S[(size_t)src*F_DIM + k0+tx];
    }
    __syncthreads();
    #pragma unroll
    for (int j = 0; j < 32; j += 8) St[(size_t)(k0+ty+j)*N_G + m0+tx] = t[tx][ty+j];
}

// ---------------------------------------------------------------------------
// Kernel 4c: Gv[m][o] = sum_k St[k][m] * Wt[k][o], output bf16.
//   grid (8 o-groups, 64 m-groups), 256 threads = 4 waves; K split 4 ways.
// ---------------------------------------------------------------------------
__global__ __launch_bounds__(256) void gemmG_kernel(const float* __restrict__ Wt,
                                                    const float* __restrict__ St,
                                                    __hip_bfloat16* __restrict__ Gvb)
{
    __shared__ float red[3][16][64];

    const int t    = threadIdx.x;
    const int lane = t & 63;
    const int wv   = t >> 6;
    const int o    = blockIdx.x*64 + lane;
    const int m0   = blockIdx.y*16;

    float acc[16];
    #pragma unroll
    for (int i = 0; i < 16; ++i) acc[i] = 0.f;

    const int kbeg = wv*128;
    #pragma unroll 4
    for (int k = kbeg; k < kbeg + 128; ++k) {
        float wvv = Wt[(size_t)k*O_DIM + o];
        const float4* sp = reinterpret_cast<const float4*>(St + (size_t)k*N_G + m0);
        float4 s0 = sp[0], s1 = sp[1], s2 = sp[2], s3 = sp[3];
        acc[0]  += s0.x*wvv; acc[1]  += s0.y*wvv; acc[2]  += s0.z*wvv; acc[3]  += s0.w*wvv;
        acc[4]  += s1.x*wvv; acc[5]  += s1.y*wvv; acc[6]  += s1.z*wvv; acc[7]  += s1.w*wvv;
        acc[8]  += s2.x*wvv; acc[9]  += s2.y*wvv; acc[10] += s2.z*wvv; acc[11] += s2.w*wvv;
        acc[12] += s3.x*wvv; acc[13] += s3.y*wvv; acc[14] += s3.z*wvv; acc[15] += s3.w*wvv;
    }

    if (wv > 0) {
        #pragma unroll
        for (int i = 0; i < 16; ++i) red[wv-1][i][lane] = acc[i];
    }
    __syncthreads();
    if (wv == 0) {
        #pragma unroll
        for (int i = 0; i < 16; ++i) {
            float v = acc[i] + red[0][i][lane] + red[1][i][lane] + red[2][i][lane];
            Gvb[(size_t)(m0+i)*O_DIM + o] = __float2bfloat16(v);
        }
    }
}

// ---------------------------------------------------------------------------
// Kernel 5: alpha/compositing (unchanged from r6)
// ---------------------------------------------------------------------------
__global__ __launch_bounds__(1024) void alpha_kernel(
    const float* __restrict__ psort, const float* __restrict__ csort,
    const float* __restrict__ bg,
    __hip_bfloat16* __restrict__ wbuf, int* __restrict__ idxl,
    int* __restrict__ cnttot, float* __restrict__ out)
{
    __shared__ float pg[N_G][8];
    __shared__ float cs[N_G][4];
    __shared__ float Pl[16][64];
    __shared__ float colbuf[16][64][4];
    __shared__ float Tfl[64];
    __shared__ int   cntl_s[16];

    const int t    = threadIdx.x;
    const int c    = t >> 6;
    const int lane = t & 63;
    const int tile = blockIdx.x;
    const int hrow = tile >> 1;
    const int w0   = (tile & 1) * 64;

    {
        float4* pgv = reinterpret_cast<float4*>(&pg[0][0]);
        const float4* ps4 = reinterpret_cast<const float4*>(psort);
        pgv[t]        = ps4[t];
        pgv[t + 1024] = ps4[t + 1024];
        float4* csv = reinterpret_cast<float4*>(&cs[0][0]);
        csv[t] = reinterpret_cast<const float4*>(csort)[t];
    }
    __syncthreads();

    const float gx = (float)(w0 + lane);
    const float gy = (float)hrow;

    float pref = 1.f;
    int cnt = 0;
    for (int j = 0; j < 64; ++j) {
        int g = c*64 + j;
        float4 A = *reinterpret_cast<const float4*>(&pg[g][0]);
        float4 B = *reinterpret_cast<const float4*>(&pg[g][4]);
        float dx = A.x - gx, dy = A.y - gy;
        float pw = -0.5f*(A.z*dx*dx + B.x*dy*dy) - A.w*dx*dy;
        float al = fminf(0.99f, B.y*__expf(pw));
        bool keep = (pw <= 0.f) && (al >= (1.f/255.f)) && (B.w > 0.5f);
        float a = keep ? al : 0.f;
        float w = pref * a;
        pref *= 1.f - a;
        cnt += (__ballot(w > 1e-12f) != 0ull) ? 1 : 0;
    }
    Pl[c][lane] = pref;
    if (lane == 0) cntl_s[c] = cnt;
    __syncthreads();

    int base = 0;
    float cp = 1.f;
    for (int cc = 0; cc < c; ++cc) {
        base += cntl_s[cc];
        cp *= Pl[cc][lane];
    }
    if (c == 15) {
        Tfl[lane] = cp * Pl[15][lane];
        if (lane == 0) {
            int tot = base + cntl_s[15];
            cnttot[tile] = (tot < MAXG) ? tot : MAXG;
        }
    }

    float pref2 = 1.f;
    int slot = base;
    float col0 = 0.f, col1 = 0.f, col2 = 0.f;
    for (int j = 0; j < 64; ++j) {
        int g = c*64 + j;
        float4 A = *reinterpret_cast<const float4*>(&pg[g][0]);
        float4 B = *reinterpret_cast<const float4*>(&pg[g][4]);
        float dx = A.x - gx, dy = A.y - gy;
        float pw = -0.5f*(A.z*dx*dx + B.x*dy*dy) - A.w*dx*dy;
        float al = fminf(0.99f, B.y*__expf(pw));
        bool keep = (pw <= 0.f) && (al >= (1.f/255.f)) && (B.w > 0.5f);
        float a = keep ? al : 0.f;
        float w = pref2 * a;
        pref2 *= 1.f - a;
        if (__ballot(w > 1e-12f) != 0ull) {
            float wfin = w * cp;
            if (slot < MAXG) {
                wbuf[((size_t)tile*MAXG + slot)*64 + lane] = __float2bfloat16(wfin);
                if (lane == 0) idxl[tile*MAXG + slot] = g;
            }
            float4 cv = *reinterpret_cast<const float4*>(&cs[g][0]);
            col0 += wfin*cv.x; col1 += wfin*cv.y; col2 += wfin*cv.z;
            ++slot;
        }
    }

    colbuf[c][lane][0] = col0; colbuf[c][lane][1] = col1; colbuf[c][lane][2] = col2;
    __syncthreads();

    if (t < 64) {
        float r = 0.f, g = 0.f, b = 0.f;
        #pragma unroll
        for (int k = 0; k < 16; ++k) {
            r += colbuf[k][t][0]; g += colbuf[k][t][1]; b += colbuf[k][t][2];
        }
        float Tf = Tfl[t];
        int pix = hrow*W_IMG + w0 + t;
        out[0*PIX + pix] = r + Tf*bg[0];
        out[1*PIX + pix] = g + Tf*bg[1];
        out[2*PIX + pix] = b + Tf*bg[2];
    }
}

// ---------------------------------------------------------------------------
// Kernel 6: per-tile feature GEMM via MFMA.
//   1 block per tile, 512 threads = 8 waves. Wave wv owns o in [64wv,64wv+64).
//   C[64px][512o] = sum_k w[px][k] * G[idx[k]][o], K = cnt padded with zeros.
//   A = G^T tile (o x k) from GT lds; B = w^T (k x px) from WT lds.
//   mfma_f32_16x16x32_bf16: A lane: row=l&15, k=8*(l>>4)+j; B lane: col=l&15,
//   k=8*(l>>4)+j; D lane: col=l&15, row=4*(l>>4)+r (m89-verified).
// ---------------------------------------------------------------------------
#define WT_PITCH 200   // shorts; 400B row stride: 16B-aligned, 2-way banks max
#define GT_PITCH 72    // shorts; 144B row stride: 16B-aligned, 2-way banks max

__global__ __launch_bounds__(512) void featgemm_kernel(
    const __hip_bfloat16* __restrict__ wbuf, const int* __restrict__ idxl,
    const int* __restrict__ cnttot, const __hip_bfloat16* __restrict__ Gvb,
    const float* __restrict__ conv_b, float* __restrict__ out)
{
    __shared__ short WT[64][WT_PITCH];    // w^T [px][k]  (25.6 KB)
    __shared__ short GT[512][GT_PITCH];   // G^T [o][k_local] (73.7 KB)
    __shared__ int   ibs[MAXG];

    const int t    = threadIdx.x;
    const int lane = t & 63;
    const int wv   = t >> 6;              // 0..7
    const int tile = blockIdx.x;
    const int cnt  = cnttot[tile];

    const short* wbs = (const short*)(wbuf + (size_t)tile*MAXG*64);
    const short* gvs = (const short*)Gvb;

    if (t < MAXG) ibs[t] = (t < cnt) ? idxl[tile*MAXG + t] : 0;

    // ---- stage WT[px][k] = w[k][px], zero-padded to MAXG ----
    {
        const int px = lane;
        const int kg = wv;                // 8 groups x 24 k
        #pragma unroll
        for (int b = 0; b < 3; ++b) {
            bf16x8 s;
            #pragma unroll
            for (int j = 0; j < 8; ++j) {
                int k = kg*24 + b*8 + j;
                s[j] = (k < cnt) ? wbs[k*64 + px] : (short)0;
            }
            *(bf16x8*)&WT[px][kg*24 + b*8] = s;
        }
    }
    __syncthreads();

    f32x4 acc[4][4];
    #pragma unroll
    for (int i = 0; i < 4; ++i)
        #pragma unroll
        for (int j = 0; j < 4; ++j)
            acc[i][j] = (f32x4){0.f,0.f,0.f,0.f};

    const int nchunk = (cnt + 63) >> 6;
    for (int c = 0; c < nchunk; ++c) {
        const int kbase = c*64;
        // ---- stage GT[o][kl] = G[idx[kbase+kl]][o], zero-padded ----
        {
            const int o = t;              // 512 threads = 512 o
            #pragma unroll
            for (int b = 0; b < 8; ++b) {
                bf16x8 s;
                #pragma unroll
                for (int j = 0; j < 8; ++j) {
                    int k = kbase + b*8 + j;
                    s[j] = (k < cnt) ? gvs[(size_t)ibs[k]*O_DIM + o] : (short)0;
                }
                *(bf16x8*)&GT[o][b*8] = s;
            }
        }
        __syncthreads();

        #pragma unroll
        for (int ks = 0; ks < 2; ++ks) {
            const int kf = 8*(lane>>4);
            bf16x8 bf[4];
            #pragma unroll
            for (int pt = 0; pt < 4; ++pt)
                bf[pt] = *(const bf16x8*)&WT[pt*16 + (lane&15)][kbase + ks*32 + kf];
            #pragma unroll
            for (int ot = 0; ot < 4; ++ot) {
                bf16x8 af = *(const bf16x8*)&GT[wv*64 + ot*16 + (lane&15)][ks*32 + kf];
                #pragma unroll
                for (int pt = 0; pt < 4; ++pt)
                    acc[ot][pt] = __builtin_amdgcn_mfma_f32_16x16x32_bf16(
                        af, bf[pt], acc[ot][pt], 0, 0, 0);
            }
        }
        __syncthreads();
    }

    // ---- epilogue: D[o_row][px_col] + conv_b ----
    const int pixbase = (tile >> 1)*W_IMG + (tile & 1)*64;
    #pragma unroll
    for (int ot = 0; ot < 4; ++ot) {
        #pragma unroll
        for (int r = 0; r < 4; ++r) {
            int o = wv*64 + ot*16 + 4*(lane>>4) + r;
            float cb = conv_b[o];
            #pragma unroll
            for (int pt = 0; pt < 4; ++pt) {
                out[FEAT_OFF + (size_t)o*PIX + pixbase + pt*16 + (lane&15)]
                    = acc[ot][pt][r] + cb;
            }
        }
    }
}

// ---------------------------------------------------------------------------
extern "C" void kernel_launch(void* const* d_in, const int* in_sizes, int n_in,
                              void* d_out, int out_size, void* d_ws, size_t ws_size,
                              hipStream_t stream)
{
    const float* means  = (const float*)d_in[0];
    const float* opac   = (const float*)d_in[2];
    const float* colors = (const float*)d_in[3];
    const float* sem    = (const float*)d_in[4];
    const float* scales = (const float*)d_in[5];
    const float* rots   = (const float*)d_in[6];
    const float* view   = (const float*)d_in[7];
    const float* proj   = (const float*)d_in[8];
    const float* bg     = (const float*)d_in[9];
    const float* conv_w = (const float*)d_in[11];
    const float* conv_b = (const float*)d_in[12];
    float* out = (float*)d_out;

    float* wsf     = (float*)d_ws;
    float* params8 = wsf;                    // 8192
    float* psort   = wsf + 8192;             // 8192
    float* csort   = wsf + 16384;            // 4096
    int*   order   = (int*)(wsf + 20480);    // 1024 ints
    int*   cnttot  = (int*)(wsf + 21504);    // 256 ints
    float* Wt      = wsf + 24576;            // 512*512 f32
    float* St      = wsf + 286720;           // 512*1024 f32
    __hip_bfloat16* Gvb = (__hip_bfloat16*)(wsf + 811008);   // 1024*512 bf16 (262144 f32 slots)
    int*   idxl    = (int*)(wsf + 1073152);  // 256*192 ints
    __hip_bfloat16* wbuf = (__hip_bfloat16*)(wsf + 1122304); // 256*192*64 bf16

    float* radii_out = out + RAD_OFF;

    prep_kernel<<<4, 256, 0, stream>>>(means, opac, scales, rots, view, proj,
                                       params8, radii_out);
    transposeW_kernel<<<dim3(16,16), dim3(32,8), 0, stream>>>(conv_w, Wt);
    rank_kernel<<<4, 256, 0, stream>>>(params8, order);
    pack_kernel<<<4, 256, 0, stream>>>(params8, colors, order, psort, csort);
    transposeS_kernel<<<dim3(16,32), dim3(32,8), 0, stream>>>(sem, order, St);
    gemmG_kernel<<<dim3(8,64), 256, 0, stream>>>(Wt, St, Gvb);
    alpha_kernel<<<256, 1024, 0, stream>>>(psort, csort, bg, wbuf, idxl, cnttot, out);
    featgemm_kernel<<<256, 512, 0, stream>>>(wbuf, idxl, cnttot, Gvb, conv_b, out);
}

// Round 11
// 127.963 us; speedup vs baseline: 1.5499x; 1.0143x over previous
//
#include <hip/hip_runtime.h>
#include <hip/hip_bf16.h>
#include <math.h>

#define H_IMG 128
#define W_IMG 128
#define N_G   1024
#define F_DIM 512
#define O_DIM 512
#define PIX   (H_IMG*W_IMG)        // 16384
#define FEAT_OFF 49152             // 3*PIX
#define RAD_OFF  (49152 + 512*16384)
#define MAXG  192                  // per-tile survivor cap (mean ~70, validated r2-r7)

typedef __attribute__((ext_vector_type(8))) short bf16x8;
typedef __attribute__((ext_vector_type(4))) float f32x4;

// ---------------------------------------------------------------------------
// Kernel 1: per-gaussian preprocessing (projection, conic, radii)  [r7-exact]
// ---------------------------------------------------------------------------
__global__ void prep_kernel(const float* __restrict__ means,
                            const float* __restrict__ opac,
                            const float* __restrict__ scales,
                            const float* __restrict__ rots,
                            const float* __restrict__ view,
                            const float* __restrict__ proj,
                            float* __restrict__ params8,
                            float* __restrict__ radii_out)
{
    int n = blockIdx.x * blockDim.x + threadIdx.x;
    if (n >= N_G) return;

    float x = means[3*n], y = means[3*n+1], z = means[3*n+2];
    float pv0 = x*view[0] + y*view[4] + z*view[8]  + view[12];
    float pv1 = x*view[1] + y*view[5] + z*view[9]  + view[13];
    float pv2 = x*view[2] + y*view[6] + z*view[10] + view[14];
    float ph0 = x*proj[0] + y*proj[4] + z*proj[8]  + proj[12];
    float ph1 = x*proj[1] + y*proj[5] + z*proj[9]  + proj[13];
    float phw = x*proj[3] + y*proj[7] + z*proj[11] + proj[15];
    float denom = phw + 1e-7f;
    float pp0 = ph0/denom, pp1 = ph1/denom;
    float depth = pv2;

    float qr=rots[4*n], qx=rots[4*n+1], qy=rots[4*n+2], qz=rots[4*n+3];
    float qn = sqrtf(qr*qr+qx*qx+qy*qy+qz*qz);
    qr/=qn; qx/=qn; qy/=qn; qz/=qn;
    float R00=1.f-2.f*(qy*qy+qz*qz), R01=2.f*(qx*qy-qr*qz), R02=2.f*(qx*qz+qr*qy);
    float R10=2.f*(qx*qy+qr*qz), R11=1.f-2.f*(qx*qx+qz*qz), R12=2.f*(qy*qz-qr*qx);
    float R20=2.f*(qx*qz-qr*qy), R21=2.f*(qy*qz+qr*qx), R22=1.f-2.f*(qx*qx+qy*qy);
    float s0=scales[3*n], s1=scales[3*n+1], s2=scales[3*n+2];
    float M00=R00*s0, M01=R01*s1, M02=R02*s2;
    float M10=R10*s0, M11=R11*s1, M12=R12*s2;
    float M20=R20*s0, M21=R21*s1, M22=R22*s2;
    float c00=M00*M00+M01*M01+M02*M02;
    float c01=M00*M10+M01*M11+M02*M12;
    float c02=M00*M20+M01*M21+M02*M22;
    float c11=M10*M10+M11*M11+M12*M12;
    float c12=M10*M20+M11*M21+M12*M22;
    float c22=M20*M20+M21*M21+M22*M22;

    const float fx=128.f, fy=128.f;
    float tz = pv2;
    float txz = fminf(fmaxf(pv0/tz, -0.65f), 0.65f) * tz;
    float tyz = fminf(fmaxf(pv1/tz, -0.65f), 0.65f) * tz;
    float J00 = fx/tz,  J02 = -fx*txz/(tz*tz);
    float J11 = fy/tz,  J12 = -fy*tyz/(tz*tz);
    float T00=J00*view[0] + J02*view[2];
    float T01=J00*view[4] + J02*view[6];
    float T02=J00*view[8] + J02*view[10];
    float T10=J11*view[1] + J12*view[2];
    float T11=J11*view[5] + J12*view[6];
    float T12=J11*view[9] + J12*view[10];
    float u0 = T00*c00 + T01*c01 + T02*c02;
    float u1 = T00*c01 + T01*c11 + T02*c12;
    float u2 = T00*c02 + T01*c12 + T02*c22;
    float v0 = T10*c00 + T11*c01 + T12*c02;
    float v1 = T10*c01 + T11*c11 + T12*c12;
    float v2 = T10*c02 + T11*c12 + T12*c22;
    float a00 = u0*T00 + u1*T01 + u2*T02 + 0.3f;
    float a01 = u0*T10 + u1*T11 + u2*T12;
    float a11 = v0*T10 + v1*T11 + v2*T12 + 0.3f;

    float det = a00*a11 - a01*a01;
    float dsafe = (det==0.f) ? 1.f : det;
    float inv = 1.f/dsafe;
    float con0 =  a11*inv, con1 = -a01*inv, con2 = a00*inv;
    float mid = 0.5f*(a00+a11);
    float lam1 = mid + sqrtf(fmaxf(0.1f, mid*mid - det));
    int irad = (int)ceilf(3.f*sqrtf(lam1));
    float pxc = ((pp0+1.f)*128.f - 1.f)*0.5f;
    float pyc = ((pp1+1.f)*128.f - 1.f)*0.5f;
    bool valid = (depth > 0.2f) && (det != 0.f);

    radii_out[n] = valid ? (float)irad : 0.f;
    float* p = params8 + 8*n;
    p[0]=pxc; p[1]=pyc; p[2]=con0; p[3]=con1; p[4]=con2;
    p[5]=opac[n]; p[6]=depth; p[7]= valid ? 1.f : 0.f;
}

// ---------------------------------------------------------------------------
// Kernel 2: fused rank sort + pack. Thread n computes rank r and scatters its
// own params/colors to slot r (identical output to rank+pack; one dispatch).
// ---------------------------------------------------------------------------
__global__ void rankpack_kernel(const float* __restrict__ params8,
                                const float* __restrict__ colors,
                                int* __restrict__ order,
                                float* __restrict__ psort,
                                float* __restrict__ csort)
{
    __shared__ float d[N_G];
    int t = threadIdx.x;
    for (int i = t; i < N_G; i += 256) d[i] = params8[8*i+6];
    __syncthreads();
    int n = blockIdx.x*256 + t;
    float dn = d[n];
    int r = 0;
    for (int m = 0; m < N_G; ++m) {
        float dm = d[m];
        r += (dm < dn) || (dm == dn && m < n);
    }
    order[r] = n;
    #pragma unroll
    for (int j = 0; j < 8; ++j) psort[8*r+j] = params8[8*n+j];
    csort[4*r+0] = colors[3*n+0];
    csort[4*r+1] = colors[3*n+1];
    csort[4*r+2] = colors[3*n+2];
    csort[4*r+3] = 0.f;
}

// ---------------------------------------------------------------------------
// Kernel 3a: Wt[k][o] = conv_w[o][k]   (512x512 transpose)  [r7-exact]
// ---------------------------------------------------------------------------
__global__ __launch_bounds__(256) void transposeW_kernel(const float* __restrict__ in,
                                                         float* __restrict__ outT)
{
    __shared__ float t[32][33];
    int k0 = blockIdx.x*32, o0 = blockIdx.y*32;
    int tx = threadIdx.x, ty = threadIdx.y;   // 32 x 8
    #pragma unroll
    for (int j = 0; j < 32; j += 8) t[ty+j][tx] = in[(size_t)(o0+ty+j)*F_DIM + k0+tx];
    __syncthreads();
    #pragma unroll
    for (int j = 0; j < 32; j += 8) outT[(size_t)(k0+ty+j)*O_DIM + o0+tx] = t[tx][ty+j];
}

// ---------------------------------------------------------------------------
// Kernel 3b: St[k][m] = S[order[m]][k]  (gathered transpose)  [r7-exact]
// ---------------------------------------------------------------------------
__global__ __launch_bounds__(256) void transposeS_kernel(const float* __restrict__ S,
                                                         const int* __restrict__ order,
                                                         float* __restrict__ St)
{
    __shared__ float t[32][33];
    int k0 = blockIdx.x*32, m0 = blockIdx.y*32;
    int tx = threadIdx.x, ty = threadIdx.y;   // 32 x 8
    #pragma unroll
    for (int j = 0; j < 32; j += 8) {
        int src = order[m0+ty+j] & (N_G - 1);
        t[ty+j][tx] = S[(size_t)src*F_DIM + k0+tx];
    }
    __syncthreads();
    #pragma unroll
    for (int j = 0; j < 32; j += 8) St[(size_t)(k0+ty+j)*N_G + m0+tx] = t[tx][ty+j];
}

// ---------------------------------------------------------------------------
// Kernel 3c: Gv[m][o] = sum_k St[k][m] * Wt[k][o], bf16 out  [r7-exact]
//   grid (8 o-groups, 64 m-groups), 4 waves; K split 4 ways + LDS reduce.
// ---------------------------------------------------------------------------
__global__ __launch_bounds__(256) void gemmG_kernel(const float* __restrict__ Wt,
                                                    const float* __restrict__ St,
                                                    __hip_bfloat16* __restrict__ Gvb)
{
    __shared__ float red[3][16][64];

    const int t    = threadIdx.x;
    const int lane = t & 63;
    const int wv   = t >> 6;
    const int o    = blockIdx.x*64 + lane;
    const int m0   = blockIdx.y*16;

    float acc[16];
    #pragma unroll
    for (int i = 0; i < 16; ++i) acc[i] = 0.f;

    const int kbeg = wv*128;
    #pragma unroll 4
    for (int k = kbeg; k < kbeg + 128; ++k) {
        float wvv = Wt[(size_t)k*O_DIM + o];
        const float4* sp = reinterpret_cast<const float4*>(St + (size_t)k*N_G + m0);
        float4 s0 = sp[0], s1 = sp[1], s2 = sp[2], s3 = sp[3];
        acc[0]  += s0.x*wvv; acc[1]  += s0.y*wvv; acc[2]  += s0.z*wvv; acc[3]  += s0.w*wvv;
        acc[4]  += s1.x*wvv; acc[5]  += s1.y*wvv; acc[6]  += s1.z*wvv; acc[7]  += s1.w*wvv;
        acc[8]  += s2.x*wvv; acc[9]  += s2.y*wvv; acc[10] += s2.z*wvv; acc[11] += s2.w*wvv;
        acc[12] += s3.x*wvv; acc[13] += s3.y*wvv; acc[14] += s3.z*wvv; acc[15] += s3.w*wvv;
    }

    if (wv > 0) {
        #pragma unroll
        for (int i = 0; i < 16; ++i) red[wv-1][i][lane] = acc[i];
    }
    __syncthreads();
    if (wv == 0) {
        #pragma unroll
        for (int i = 0; i < 16; ++i) {
            float v = acc[i] + red[0][i][lane] + red[1][i][lane] + red[2][i][lane];
            Gvb[(size_t)(m0+i)*O_DIM + o] = __float2bfloat16(v);
        }
    }
}

// ---------------------------------------------------------------------------
// Kernel 4: alpha/compositing  [r7-exact]
// ---------------------------------------------------------------------------
__global__ __launch_bounds__(1024) void alpha_kernel(
    const float* __restrict__ psort, const float* __restrict__ csort,
    const float* __restrict__ bg,
    __hip_bfloat16* __restrict__ wbuf, int* __restrict__ idxl,
    int* __restrict__ cnttot, float* __restrict__ out)
{
    __shared__ float pg[N_G][8];
    __shared__ float cs[N_G][4];
    __shared__ float Pl[16][64];
    __shared__ float colbuf[16][64][4];
    __shared__ float Tfl[64];
    __shared__ int   cntl_s[16];

    const int t    = threadIdx.x;
    const int c    = t >> 6;
    const int lane = t & 63;
    const int tile = blockIdx.x;
    const int hrow = tile >> 1;
    const int w0   = (tile & 1) * 64;

    {
        float4* pgv = reinterpret_cast<float4*>(&pg[0][0]);
        const float4* ps4 = reinterpret_cast<const float4*>(psort);
        pgv[t]        = ps4[t];
        pgv[t + 1024] = ps4[t + 1024];
        float4* csv = reinterpret_cast<float4*>(&cs[0][0]);
        csv[t] = reinterpret_cast<const float4*>(csort)[t];
    }
    __syncthreads();

    const float gx = (float)(w0 + lane);
    const float gy = (float)hrow;

    float pref = 1.f;
    int cnt = 0;
    for (int j = 0; j < 64; ++j) {
        int g = c*64 + j;
        float4 A = *reinterpret_cast<const float4*>(&pg[g][0]);
        float4 B = *reinterpret_cast<const float4*>(&pg[g][4]);
        float dx = A.x - gx, dy = A.y - gy;
        float pw = -0.5f*(A.z*dx*dx + B.x*dy*dy) - A.w*dx*dy;
        float al = fminf(0.99f, B.y*__expf(pw));
        bool keep = (pw <= 0.f) && (al >= (1.f/255.f)) && (B.w > 0.5f);
        float a = keep ? al : 0.f;
        float w = pref * a;
        pref *= 1.f - a;
        cnt += (__ballot(w > 1e-12f) != 0ull) ? 1 : 0;
    }
    Pl[c][lane] = pref;
    if (lane == 0) cntl_s[c] = cnt;
    __syncthreads();

    int base = 0;
    float cp = 1.f;
    for (int cc = 0; cc < c; ++cc) {
        base += cntl_s[cc];
        cp *= Pl[cc][lane];
    }
    if (c == 15) {
        Tfl[lane] = cp * Pl[15][lane];
        if (lane == 0) {
            int tot = base + cntl_s[15];
            cnttot[tile] = (tot < MAXG) ? tot : MAXG;
        }
    }

    float pref2 = 1.f;
    int slot = base;
    float col0 = 0.f, col1 = 0.f, col2 = 0.f;
    for (int j = 0; j < 64; ++j) {
        int g = c*64 + j;
        float4 A = *reinterpret_cast<const float4*>(&pg[g][0]);
        float4 B = *reinterpret_cast<const float4*>(&pg[g][4]);
        float dx = A.x - gx, dy = A.y - gy;
        float pw = -0.5f*(A.z*dx*dx + B.x*dy*dy) - A.w*dx*dy;
        float al = fminf(0.99f, B.y*__expf(pw));
        bool keep = (pw <= 0.f) && (al >= (1.f/255.f)) && (B.w > 0.5f);
        float a = keep ? al : 0.f;
        float w = pref2 * a;
        pref2 *= 1.f - a;
        if (__ballot(w > 1e-12f) != 0ull) {
            float wfin = w * cp;
            if (slot < MAXG) {
                wbuf[((size_t)tile*MAXG + slot)*64 + lane] = __float2bfloat16(wfin);
                if (lane == 0) idxl[tile*MAXG + slot] = g;
            }
            float4 cv = *reinterpret_cast<const float4*>(&cs[g][0]);
            col0 += wfin*cv.x; col1 += wfin*cv.y; col2 += wfin*cv.z;
            ++slot;
        }
    }

    colbuf[c][lane][0] = col0; colbuf[c][lane][1] = col1; colbuf[c][lane][2] = col2;
    __syncthreads();

    if (t < 64) {
        float r = 0.f, g = 0.f, b = 0.f;
        #pragma unroll
        for (int k = 0; k < 16; ++k) {
            r += colbuf[k][t][0]; g += colbuf[k][t][1]; b += colbuf[k][t][2];
        }
        float Tf = Tfl[t];
        int pix = hrow*W_IMG + w0 + t;
        out[0*PIX + pix] = r + Tf*bg[0];
        out[1*PIX + pix] = g + Tf*bg[1];
        out[2*PIX + pix] = b + Tf*bg[2];
    }
}

// ---------------------------------------------------------------------------
// Kernel 5: per-tile feature GEMM via MFMA  [r7-exact core + safe clamps]
// ---------------------------------------------------------------------------
#define WT_PITCH 200   // shorts; 400B row stride
#define GT_PITCH 72    // shorts; 144B row stride

__global__ __launch_bounds__(512) void featgemm_kernel(
    const __hip_bfloat16* __restrict__ wbuf, const int* __restrict__ idxl,
    const int* __restrict__ cnttot, const __hip_bfloat16* __restrict__ Gvb,
    const float* __restrict__ conv_b, float* __restrict__ out)
{
    __shared__ short WT[64][WT_PITCH];
    __shared__ short GT[512][GT_PITCH];
    __shared__ int   ibs[MAXG];

    const int t    = threadIdx.x;
    const int lane = t & 63;
    const int wv   = t >> 6;
    const int tile = blockIdx.x;
    int cnt = cnttot[tile];
    cnt = (cnt < 0) ? 0 : ((cnt > MAXG) ? MAXG : cnt);

    const short* wbs = (const short*)(wbuf + (size_t)tile*MAXG*64);
    const short* gvs = (const short*)Gvb;

    if (t < MAXG) ibs[t] = (t < cnt) ? (idxl[tile*MAXG + t] & (N_G - 1)) : 0;

    {
        const int px = lane;
        const int kg = wv;
        #pragma unroll
        for (int b = 0; b < 3; ++b) {
            bf16x8 s;
            #pragma unroll
            for (int j = 0; j < 8; ++j) {
                int k = kg*24 + b*8 + j;
                s[j] = (k < cnt) ? wbs[k*64 + px] : (short)0;
            }
            *(bf16x8*)&WT[px][kg*24 + b*8] = s;
        }
    }
    __syncthreads();

    f32x4 acc[4][4];
    #pragma unroll
    for (int i = 0; i < 4; ++i)
        #pragma unroll
        for (int j = 0; j < 4; ++j)
            acc[i][j] = (f32x4){0.f,0.f,0.f,0.f};

    const int nchunk = (cnt + 63) >> 6;
    for (int c = 0; c < nchunk; ++c) {
        const int kbase = c*64;
        {
            const int o = t;
            #pragma unroll
            for (int b = 0; b < 8; ++b) {
                bf16x8 s;
                #pragma unroll
                for (int j = 0; j < 8; ++j) {
                    int k = kbase + b*8 + j;
                    s[j] = (k < cnt) ? gvs[(size_t)ibs[k]*O_DIM + o] : (short)0;
                }
                *(bf16x8*)&GT[o][b*8] = s;
            }
        }
        __syncthreads();

        #pragma unroll
        for (int ks = 0; ks < 2; ++ks) {
            const int kf = 8*(lane>>4);
            bf16x8 bfr[4];
            #pragma unroll
            for (int pt = 0; pt < 4; ++pt)
                bfr[pt] = *(const bf16x8*)&WT[pt*16 + (lane&15)][kbase + ks*32 + kf];
            #pragma unroll
            for (int ot = 0; ot < 4; ++ot) {
                bf16x8 af = *(const bf16x8*)&GT[wv*64 + ot*16 + (lane&15)][ks*32 + kf];
                #pragma unroll
                for (int pt = 0; pt < 4; ++pt)
                    acc[ot][pt] = __builtin_amdgcn_mfma_f32_16x16x32_bf16(
                        af, bfr[pt], acc[ot][pt], 0, 0, 0);
            }
        }
        __syncthreads();
    }

    const int pixbase = (tile >> 1)*W_IMG + (tile & 1)*64;
    #pragma unroll
    for (int ot = 0; ot < 4; ++ot) {
        #pragma unroll
        for (int r = 0; r < 4; ++r) {
            int o = wv*64 + ot*16 + 4*(lane>>4) + r;
            float cb = conv_b[o];
            #pragma unroll
            for (int pt = 0; pt < 4; ++pt) {
                out[FEAT_OFF + (size_t)o*PIX + pixbase + pt*16 + (lane&15)]
                    = acc[ot][pt][r] + cb;
            }
        }
    }
}

// ---------------------------------------------------------------------------
extern "C" void kernel_launch(void* const* d_in, const int* in_sizes, int n_in,
                              void* d_out, int out_size, void* d_ws, size_t ws_size,
                              hipStream_t stream)
{
    const float* means  = (const float*)d_in[0];
    const float* opac   = (const float*)d_in[2];
    const float* colors = (const float*)d_in[3];
    const float* sem    = (const float*)d_in[4];
    const float* scales = (const float*)d_in[5];
    const float* rots   = (const float*)d_in[6];
    const float* view   = (const float*)d_in[7];
    const float* proj   = (const float*)d_in[8];
    const float* bg     = (const float*)d_in[9];
    const float* conv_w = (const float*)d_in[11];
    const float* conv_b = (const float*)d_in[12];
    float* out = (float*)d_out;

    // --- workspace layout: r7-proven offsets (f32 slots) ---
    float* wsf     = (float*)d_ws;
    float* params8 = wsf;                    // [0, 8192)
    float* psort   = wsf + 8192;             // [8192, 16384)
    float* csort   = wsf + 16384;            // [16384, 20480)
    int*   order   = (int*)(wsf + 20480);    // [20480, 21504)
    int*   cnttot  = (int*)(wsf + 21504);    // [21504, 21760)
    float* Wt      = wsf + 24576;            // [24576, 286720)   512*512 f32
    float* St      = wsf + 286720;           // [286720, 811008)  512*1024 f32
    __hip_bfloat16* Gvb = (__hip_bfloat16*)(wsf + 811008);   // [811008, 1073152) bf16
    int*   idxl    = (int*)(wsf + 1073152);  // [1073152, 1085440)
    __hip_bfloat16* wbuf = (__hip_bfloat16*)(wsf + 1122304); // [1122304, 2695168)

    float* radii_out = out + RAD_OFF;

    prep_kernel<<<4, 256, 0, stream>>>(means, opac, scales, rots, view, proj,
                                       params8, radii_out);
    transposeW_kernel<<<dim3(16,16), dim3(32,8), 0, stream>>>(conv_w, Wt);
    rankpack_kernel<<<4, 256, 0, stream>>>(params8, colors, order, psort, csort);
    transposeS_kernel<<<dim3(16,32), dim3(32,8), 0, stream>>>(sem, order, St);
    gemmG_kernel<<<dim3(8,64), 256, 0, stream>>>(Wt, St, Gvb);
    alpha_kernel<<<256, 1024, 0, stream>>>(psort, csort, bg, wbuf, idxl, cnttot, out);
    featgemm_kernel<<<256, 512, 0, stream>>>(wbuf, idxl, cnttot, Gvb, conv_b, out);
}

// Round 12
// 114.628 us; speedup vs baseline: 1.7302x; 1.1163x over previous
//
#include <hip/hip_runtime.h>
#include <hip/hip_bf16.h>
#include <math.h>

#define H_IMG 128
#define W_IMG 128
#define N_G   1024
#define F_DIM 512
#define O_DIM 512
#define PIX   (H_IMG*W_IMG)        // 16384
#define FEAT_OFF 49152             // 3*PIX
#define RAD_OFF  (49152 + 512*16384)
#define MAXG  192                  // per-tile survivor cap (validated r2-r11)
#define WT_PITCH 200               // shorts; 400B row stride (16B-aligned)
#define GT_PITCH 72                // shorts; 144B row stride (16B-aligned)

typedef __attribute__((ext_vector_type(8))) short bf16x8;
typedef __attribute__((ext_vector_type(4))) float f32x4;

// ---------------------------------------------------------------------------
// Kernel 1: fused prep + rank + pack. 4 blocks x 256. Each block computes all
// 1024 depths (3 FMA each) into LDS; one depth definition d[n] is used for
// BOTH ranking and params (exact consistency). Thread n then runs full prep
// and scatters params/colors to its rank slot.
// ---------------------------------------------------------------------------
__global__ __launch_bounds__(256) void preprank_kernel(
    const float* __restrict__ means,
    const float* __restrict__ opac,
    const float* __restrict__ colors,
    const float* __restrict__ scales,
    const float* __restrict__ rots,
    const float* __restrict__ view,
    const float* __restrict__ proj,
    int* __restrict__ order,
    float* __restrict__ psort,
    float* __restrict__ csort,
    float* __restrict__ radii_out)
{
    __shared__ float d[N_G];
    const int t = threadIdx.x;
    const float v2 = view[2], v6 = view[6], v10 = view[10], v14 = view[14];
    for (int i = t; i < N_G; i += 256)
        d[i] = means[3*i]*v2 + means[3*i+1]*v6 + means[3*i+2]*v10 + v14;
    __syncthreads();

    const int n = blockIdx.x*256 + t;
    const float depth = d[n];

    // rank (stable argsort by depth, tie-break by index)
    int r = 0;
    for (int m = 0; m < N_G; ++m) {
        float dm = d[m];
        r += (dm < depth) || (dm == depth && m < n);
    }

    // full prep
    float x = means[3*n], y = means[3*n+1], z = means[3*n+2];
    float pv0 = x*view[0] + y*view[4] + z*view[8]  + view[12];
    float pv1 = x*view[1] + y*view[5] + z*view[9]  + view[13];
    float ph0 = x*proj[0] + y*proj[4] + z*proj[8]  + proj[12];
    float ph1 = x*proj[1] + y*proj[5] + z*proj[9]  + proj[13];
    float phw = x*proj[3] + y*proj[7] + z*proj[11] + proj[15];
    float denom = phw + 1e-7f;
    float pp0 = ph0/denom, pp1 = ph1/denom;

    float qr=rots[4*n], qx=rots[4*n+1], qy=rots[4*n+2], qz=rots[4*n+3];
    float qn = sqrtf(qr*qr+qx*qx+qy*qy+qz*qz);
    qr/=qn; qx/=qn; qy/=qn; qz/=qn;
    float R00=1.f-2.f*(qy*qy+qz*qz), R01=2.f*(qx*qy-qr*qz), R02=2.f*(qx*qz+qr*qy);
    float R10=2.f*(qx*qy+qr*qz), R11=1.f-2.f*(qx*qx+qz*qz), R12=2.f*(qy*qz-qr*qx);
    float R20=2.f*(qx*qz-qr*qy), R21=2.f*(qy*qz+qr*qx), R22=1.f-2.f*(qx*qx+qy*qy);
    float s0=scales[3*n], s1=scales[3*n+1], s2=scales[3*n+2];
    float M00=R00*s0, M01=R01*s1, M02=R02*s2;
    float M10=R10*s0, M11=R11*s1, M12=R12*s2;
    float M20=R20*s0, M21=R21*s1, M22=R22*s2;
    float c00=M00*M00+M01*M01+M02*M02;
    float c01=M00*M10+M01*M11+M02*M12;
    float c02=M00*M20+M01*M21+M02*M22;
    float c11=M10*M10+M11*M11+M12*M12;
    float c12=M10*M20+M11*M21+M12*M22;
    float c22=M20*M20+M21*M21+M22*M22;

    const float fx=128.f, fy=128.f;
    float tz = depth;
    float txz = fminf(fmaxf(pv0/tz, -0.65f), 0.65f) * tz;
    float tyz = fminf(fmaxf(pv1/tz, -0.65f), 0.65f) * tz;
    float J00 = fx/tz,  J02 = -fx*txz/(tz*tz);
    float J11 = fy/tz,  J12 = -fy*tyz/(tz*tz);
    float T00=J00*view[0] + J02*view[2];
    float T01=J00*view[4] + J02*view[6];
    float T02=J00*view[8] + J02*view[10];
    float T10=J11*view[1] + J12*view[2];
    float T11=J11*view[5] + J12*view[6];
    float T12=J11*view[9] + J12*view[10];
    float u0 = T00*c00 + T01*c01 + T02*c02;
    float u1 = T00*c01 + T01*c11 + T02*c12;
    float u2 = T00*c02 + T01*c12 + T02*c22;
    float v0 = T10*c00 + T11*c01 + T12*c02;
    float v1 = T10*c01 + T11*c11 + T12*c12;
    float v2r= T10*c02 + T11*c12 + T12*c22;
    float a00 = u0*T00 + u1*T01 + u2*T02 + 0.3f;
    float a01 = u0*T10 + u1*T11 + u2*T12;
    float a11 = v0*T10 + v1*T11 + v2r*T12 + 0.3f;

    float det = a00*a11 - a01*a01;
    float dsafe = (det==0.f) ? 1.f : det;
    float inv = 1.f/dsafe;
    float con0 =  a11*inv, con1 = -a01*inv, con2 = a00*inv;
    float mid = 0.5f*(a00+a11);
    float lam1 = mid + sqrtf(fmaxf(0.1f, mid*mid - det));
    int irad = (int)ceilf(3.f*sqrtf(lam1));
    float pxc = ((pp0+1.f)*128.f - 1.f)*0.5f;
    float pyc = ((pp1+1.f)*128.f - 1.f)*0.5f;
    bool valid = (depth > 0.2f) && (det != 0.f);

    radii_out[n] = valid ? (float)irad : 0.f;
    order[r] = n;
    float* p = psort + 8*r;
    p[0]=pxc; p[1]=pyc; p[2]=con0; p[3]=con1; p[4]=con2;
    p[5]=opac[n]; p[6]=depth; p[7]= valid ? 1.f : 0.f;
    csort[4*r+0] = colors[3*n+0];
    csort[4*r+1] = colors[3*n+1];
    csort[4*r+2] = colors[3*n+2];
    csort[4*r+3] = 0.f;
}

// ---------------------------------------------------------------------------
// Kernel 2: fused transposes. Blocks [0,256): Wt[k][o] = conv_w[o][k].
// Blocks [256,768): St[k][m] = S[order[m]][k].  dim3(32,8).
// ---------------------------------------------------------------------------
__global__ __launch_bounds__(256) void transposeWS_kernel(
    const float* __restrict__ Wm, const float* __restrict__ S,
    const int* __restrict__ order,
    float* __restrict__ Wt, float* __restrict__ St)
{
    __shared__ float tb[32][33];
    const int bid = blockIdx.x;
    const int tx = threadIdx.x, ty = threadIdx.y;
    if (bid < 256) {
        int k0 = (bid & 15)*32, o0 = (bid >> 4)*32;
        #pragma unroll
        for (int j = 0; j < 32; j += 8)
            tb[ty+j][tx] = Wm[(size_t)(o0+ty+j)*F_DIM + k0+tx];
        __syncthreads();
        #pragma unroll
        for (int j = 0; j < 32; j += 8)
            Wt[(size_t)(k0+ty+j)*O_DIM + o0+tx] = tb[tx][ty+j];
    } else {
        int id = bid - 256;
        int k0 = (id & 15)*32, m0 = (id >> 4)*32;
        #pragma unroll
        for (int j = 0; j < 32; j += 8) {
            int src = order[m0+ty+j] & (N_G - 1);
            tb[ty+j][tx] = S[(size_t)src*F_DIM + k0+tx];
        }
        __syncthreads();
        #pragma unroll
        for (int j = 0; j < 32; j += 8)
            St[(size_t)(k0+ty+j)*N_G + m0+tx] = tb[tx][ty+j];
    }
}

// ---------------------------------------------------------------------------
// Kernel 3: Gv[m][o] = sum_k St[k][m] * Wt[k][o], bf16 out  [r11-exact]
// ---------------------------------------------------------------------------
__global__ __launch_bounds__(256) void gemmG_kernel(const float* __restrict__ Wt,
                                                    const float* __restrict__ St,
                                                    __hip_bfloat16* __restrict__ Gvb)
{
    __shared__ float red[3][16][64];

    const int t    = threadIdx.x;
    const int lane = t & 63;
    const int wv   = t >> 6;
    const int o    = blockIdx.x*64 + lane;
    const int m0   = blockIdx.y*16;

    float acc[16];
    #pragma unroll
    for (int i = 0; i < 16; ++i) acc[i] = 0.f;

    const int kbeg = wv*128;
    #pragma unroll 4
    for (int k = kbeg; k < kbeg + 128; ++k) {
        float wvv = Wt[(size_t)k*O_DIM + o];
        const float4* sp = reinterpret_cast<const float4*>(St + (size_t)k*N_G + m0);
        float4 s0 = sp[0], s1 = sp[1], s2 = sp[2], s3 = sp[3];
        acc[0]  += s0.x*wvv; acc[1]  += s0.y*wvv; acc[2]  += s0.z*wvv; acc[3]  += s0.w*wvv;
        acc[4]  += s1.x*wvv; acc[5]  += s1.y*wvv; acc[6]  += s1.z*wvv; acc[7]  += s1.w*wvv;
        acc[8]  += s2.x*wvv; acc[9]  += s2.y*wvv; acc[10] += s2.z*wvv; acc[11] += s2.w*wvv;
        acc[12] += s3.x*wvv; acc[13] += s3.y*wvv; acc[14] += s3.z*wvv; acc[15] += s3.w*wvv;
    }

    if (wv > 0) {
        #pragma unroll
        for (int i = 0; i < 16; ++i) red[wv-1][i][lane] = acc[i];
    }
    __syncthreads();
    if (wv == 0) {
        #pragma unroll
        for (int i = 0; i < 16; ++i) {
            float v = acc[i] + red[0][i][lane] + red[1][i][lane] + red[2][i][lane];
            Gvb[(size_t)(m0+i)*O_DIM + o] = __float2bfloat16(v);
        }
    }
}

// ---------------------------------------------------------------------------
// Kernel 4: fused alpha + featgemm. 256 blocks x 1024 threads (16 waves).
// Alpha phase (r7-proven logic) writes weights DIRECTLY into WT LDS (no
// global wbuf) and survivor indices into LDS; featgemm phase (r7-proven
// MFMA core, 16 waves x 32 o) consumes them. GT overlays the pg/cs/colbuf
// region (phase-disjoint, barrier-separated).
// ---------------------------------------------------------------------------
__global__ __launch_bounds__(1024) void alphafeat_kernel(
    const float* __restrict__ psort, const float* __restrict__ csort,
    const float* __restrict__ bg,
    const __hip_bfloat16* __restrict__ Gvb, const float* __restrict__ conv_b,
    float* __restrict__ out)
{
    __shared__ __align__(16) char uni[73728];           // GT region (phase B)
    float (*pg)[8]       = (float(*)[8])uni;            // [0,32768)
    float (*cs)[4]       = (float(*)[4])(uni + 32768);  // [32768,49152)
    float (*colbuf)[64][4] = (float(*)[64][4])(uni + 49152); // [49152,65536)
    float (*Pl)[64]      = (float(*)[64])(uni + 65536); // [65536,69632)
    short (*GT)[GT_PITCH] = (short(*)[GT_PITCH])uni;    // 512*72*2 = 73728

    __shared__ short WT[64][WT_PITCH];                  // 25.6 KB
    __shared__ float Tfl[64];
    __shared__ int   idx_lds[MAXG];
    __shared__ int   cntl_s[16];
    __shared__ int   cnt_tot;

    const int t    = threadIdx.x;
    const int c    = t >> 6;        // wave = chunk
    const int lane = t & 63;
    const int tile = blockIdx.x;
    const int hrow = tile >> 1;
    const int w0   = (tile & 1) * 64;

    // stage params + colors; zero WT; zero idx
    {
        float4* pgv = reinterpret_cast<float4*>(&pg[0][0]);
        const float4* ps4 = reinterpret_cast<const float4*>(psort);
        pgv[t]        = ps4[t];
        pgv[t + 1024] = ps4[t + 1024];
        float4* csv = reinterpret_cast<float4*>(&cs[0][0]);
        csv[t] = reinterpret_cast<const float4*>(csort)[t];
        int* wtz = (int*)&WT[0][0];
        for (int i = t; i < 64*WT_PITCH/2; i += 1024) wtz[i] = 0;
        if (t < MAXG) idx_lds[t] = 0;
    }
    __syncthreads();

    const float gx = (float)(w0 + lane);
    const float gy = (float)hrow;

    // ---- pass 1: per-chunk transmittance + survivor count ----
    float pref = 1.f;
    int cnt = 0;
    for (int j = 0; j < 64; ++j) {
        int g = c*64 + j;
        float4 A = *reinterpret_cast<const float4*>(&pg[g][0]);
        float4 B = *reinterpret_cast<const float4*>(&pg[g][4]);
        float dx = A.x - gx, dy = A.y - gy;
        float pw = -0.5f*(A.z*dx*dx + B.x*dy*dy) - A.w*dx*dy;
        float al = fminf(0.99f, B.y*__expf(pw));
        bool keep = (pw <= 0.f) && (al >= (1.f/255.f)) && (B.w > 0.5f);
        float a = keep ? al : 0.f;
        float w = pref * a;
        pref *= 1.f - a;
        cnt += (__ballot(w > 1e-12f) != 0ull) ? 1 : 0;
    }
    Pl[c][lane] = pref;
    if (lane == 0) cntl_s[c] = cnt;
    __syncthreads();

    int base = 0;
    float cp = 1.f;
    for (int cc = 0; cc < c; ++cc) {
        base += cntl_s[cc];
        cp *= Pl[cc][lane];
    }
    if (c == 15) {
        Tfl[lane] = cp * Pl[15][lane];
        if (lane == 0) {
            int tot = base + cntl_s[15];
            cnt_tot = (tot < MAXG) ? tot : MAXG;
        }
    }

    // ---- pass 2: weights -> WT LDS (transposed layout), color accum ----
    float pref2 = 1.f;
    int slot = base;
    float col0 = 0.f, col1 = 0.f, col2 = 0.f;
    for (int j = 0; j < 64; ++j) {
        int g = c*64 + j;
        float4 A = *reinterpret_cast<const float4*>(&pg[g][0]);
        float4 B = *reinterpret_cast<const float4*>(&pg[g][4]);
        float dx = A.x - gx, dy = A.y - gy;
        float pw = -0.5f*(A.z*dx*dx + B.x*dy*dy) - A.w*dx*dy;
        float al = fminf(0.99f, B.y*__expf(pw));
        bool keep = (pw <= 0.f) && (al >= (1.f/255.f)) && (B.w > 0.5f);
        float a = keep ? al : 0.f;
        float w = pref2 * a;
        pref2 *= 1.f - a;
        if (__ballot(w > 1e-12f) != 0ull) {
            float wfin = w * cp;
            if (slot < MAXG) {
                WT[lane][slot] = __bfloat16_as_short(__float2bfloat16(wfin));
                if (lane == 0) idx_lds[slot] = g;
            }
            float4 cv = *reinterpret_cast<const float4*>(&cs[g][0]);
            col0 += wfin*cv.x; col1 += wfin*cv.y; col2 += wfin*cv.z;
            ++slot;
        }
    }

    colbuf[c][lane][0] = col0; colbuf[c][lane][1] = col1; colbuf[c][lane][2] = col2;
    __syncthreads();

    if (t < 64) {
        float r = 0.f, g = 0.f, b = 0.f;
        #pragma unroll
        for (int k = 0; k < 16; ++k) {
            r += colbuf[k][t][0]; g += colbuf[k][t][1]; b += colbuf[k][t][2];
        }
        float Tf = Tfl[t];
        int pix = hrow*W_IMG + w0 + t;
        out[0*PIX + pix] = r + Tf*bg[0];
        out[1*PIX + pix] = g + Tf*bg[1];
        out[2*PIX + pix] = b + Tf*bg[2];
    }
    __syncthreads();    // colbuf/pg/cs dead; WT/idx/cnt_tot visible

    // ---- featgemm phase: 16 waves x 32 o ----
    int scnt = cnt_tot;
    scnt = (scnt < 0) ? 0 : ((scnt > MAXG) ? MAXG : scnt);
    const short* gvs = (const short*)Gvb;

    f32x4 acc[2][4];
    #pragma unroll
    for (int i = 0; i < 2; ++i)
        #pragma unroll
        for (int j = 0; j < 4; ++j)
            acc[i][j] = (f32x4){0.f,0.f,0.f,0.f};

    const int nchunk = (scnt + 63) >> 6;
    for (int cc = 0; cc < nchunk; ++cc) {
        const int kbase = cc*64;
        // stage GT[o][k_local]: o = t&511, half = t>>9 covers 32 k each
        {
            const int o = t & 511;
            const int half = t >> 9;
            #pragma unroll
            for (int b = 0; b < 4; ++b) {
                bf16x8 s;
                #pragma unroll
                for (int j = 0; j < 8; ++j) {
                    int k = kbase + half*32 + b*8 + j;
                    s[j] = (k < scnt) ? gvs[(size_t)idx_lds[k]*O_DIM + o] : (short)0;
                }
                *(bf16x8*)&GT[o][half*32 + b*8] = s;
            }
        }
        __syncthreads();

        #pragma unroll
        for (int ks = 0; ks < 2; ++ks) {
            const int kf = 8*(lane>>4);
            bf16x8 bfr[4];
            #pragma unroll
            for (int pt = 0; pt < 4; ++pt)
                bfr[pt] = *(const bf16x8*)&WT[pt*16 + (lane&15)][kbase + ks*32 + kf];
            #pragma unroll
            for (int ot = 0; ot < 2; ++ot) {
                bf16x8 af = *(const bf16x8*)&GT[c*32 + ot*16 + (lane&15)][ks*32 + kf];
                #pragma unroll
                for (int pt = 0; pt < 4; ++pt)
                    acc[ot][pt] = __builtin_amdgcn_mfma_f32_16x16x32_bf16(
                        af, bfr[pt], acc[ot][pt], 0, 0, 0);
            }
        }
        __syncthreads();
    }

    const int pixbase = hrow*W_IMG + w0;
    #pragma unroll
    for (int ot = 0; ot < 2; ++ot) {
        #pragma unroll
        for (int r = 0; r < 4; ++r) {
            int o = c*32 + ot*16 + 4*(lane>>4) + r;
            float cb = conv_b[o];
            #pragma unroll
            for (int pt = 0; pt < 4; ++pt) {
                out[FEAT_OFF + (size_t)o*PIX + pixbase + pt*16 + (lane&15)]
                    = acc[ot][pt][r] + cb;
            }
        }
    }
}

// ---------------------------------------------------------------------------
extern "C" void kernel_launch(void* const* d_in, const int* in_sizes, int n_in,
                              void* d_out, int out_size, void* d_ws, size_t ws_size,
                              hipStream_t stream)
{
    const float* means  = (const float*)d_in[0];
    const float* opac   = (const float*)d_in[2];
    const float* colors = (const float*)d_in[3];
    const float* sem    = (const float*)d_in[4];
    const float* scales = (const float*)d_in[5];
    const float* rots   = (const float*)d_in[6];
    const float* view   = (const float*)d_in[7];
    const float* proj   = (const float*)d_in[8];
    const float* bg     = (const float*)d_in[9];
    const float* conv_w = (const float*)d_in[11];
    const float* conv_b = (const float*)d_in[12];
    float* out = (float*)d_out;

    // --- workspace layout (f32 slots) ---
    // psort:      0 ..   8192
    // csort:   8192 ..  12288
    // order:  12288 ..  13312   (1024 ints)
    // Wt:     16384 .. 278528   (512*512 f32)
    // St:    278528 .. 802816   (512*1024 f32)
    // Gvb:   802816 .. 1064960  (1024*512 bf16 = 262144 f32 slots)
    float* wsf   = (float*)d_ws;
    float* psort = wsf;
    float* csort = wsf + 8192;
    int*   order = (int*)(wsf + 12288);
    float* Wt    = wsf + 16384;
    float* St    = wsf + 278528;
    __hip_bfloat16* Gvb = (__hip_bfloat16*)(wsf + 802816);

    float* radii_out = out + RAD_OFF;

    preprank_kernel<<<4, 256, 0, stream>>>(means, opac, colors, scales, rots,
                                           view, proj, order, psort, csort,
                                           radii_out);
    transposeWS_kernel<<<768, dim3(32,8), 0, stream>>>(conv_w, sem, order, Wt, St);
    gemmG_kernel<<<dim3(8,64), 256, 0, stream>>>(Wt, St, Gvb);
    alphafeat_kernel<<<256, 1024, 0, stream>>>(psort, csort, bg, Gvb, conv_b, out);
}

// Round 13
// 110.482 us; speedup vs baseline: 1.7951x; 1.0375x over previous
//
#include <hip/hip_runtime.h>
#include <hip/hip_bf16.h>
#include <math.h>

#define H_IMG 128
#define W_IMG 128
#define N_G   1024
#define F_DIM 512
#define O_DIM 512
#define PIX   (H_IMG*W_IMG)        // 16384
#define FEAT_OFF 49152             // 3*PIX
#define RAD_OFF  (49152 + 512*16384)
#define MAXG  192                  // per-tile survivor cap (validated r2-r12)
#define WT_PITCH 200               // shorts; 400B row stride (16B-aligned)
#define GT_PITCH 72                // shorts; 144B row stride (16B-aligned)

typedef __attribute__((ext_vector_type(8))) short bf16x8;
typedef __attribute__((ext_vector_type(4))) float f32x4;

// ---------------------------------------------------------------------------
// Kernel 1: fused prep + rank + pack  [r12-exact]
// ---------------------------------------------------------------------------
__global__ __launch_bounds__(256) void preprank_kernel(
    const float* __restrict__ means,
    const float* __restrict__ opac,
    const float* __restrict__ colors,
    const float* __restrict__ scales,
    const float* __restrict__ rots,
    const float* __restrict__ view,
    const float* __restrict__ proj,
    int* __restrict__ order,
    float* __restrict__ psort,
    float* __restrict__ csort,
    float* __restrict__ radii_out)
{
    __shared__ float d[N_G];
    const int t = threadIdx.x;
    const float v2 = view[2], v6 = view[6], v10 = view[10], v14 = view[14];
    for (int i = t; i < N_G; i += 256)
        d[i] = means[3*i]*v2 + means[3*i+1]*v6 + means[3*i+2]*v10 + v14;
    __syncthreads();

    const int n = blockIdx.x*256 + t;
    const float depth = d[n];

    int r = 0;
    for (int m = 0; m < N_G; ++m) {
        float dm = d[m];
        r += (dm < depth) || (dm == depth && m < n);
    }

    float x = means[3*n], y = means[3*n+1], z = means[3*n+2];
    float pv0 = x*view[0] + y*view[4] + z*view[8]  + view[12];
    float pv1 = x*view[1] + y*view[5] + z*view[9]  + view[13];
    float ph0 = x*proj[0] + y*proj[4] + z*proj[8]  + proj[12];
    float ph1 = x*proj[1] + y*proj[5] + z*proj[9]  + proj[13];
    float phw = x*proj[3] + y*proj[7] + z*proj[11] + proj[15];
    float denom = phw + 1e-7f;
    float pp0 = ph0/denom, pp1 = ph1/denom;

    float qr=rots[4*n], qx=rots[4*n+1], qy=rots[4*n+2], qz=rots[4*n+3];
    float qn = sqrtf(qr*qr+qx*qx+qy*qy+qz*qz);
    qr/=qn; qx/=qn; qy/=qn; qz/=qn;
    float R00=1.f-2.f*(qy*qy+qz*qz), R01=2.f*(qx*qy-qr*qz), R02=2.f*(qx*qz+qr*qy);
    float R10=2.f*(qx*qy+qr*qz), R11=1.f-2.f*(qx*qx+qz*qz), R12=2.f*(qy*qz-qr*qx);
    float R20=2.f*(qx*qz-qr*qy), R21=2.f*(qy*qz+qr*qx), R22=1.f-2.f*(qx*qx+qy*qy);
    float s0=scales[3*n], s1=scales[3*n+1], s2=scales[3*n+2];
    float M00=R00*s0, M01=R01*s1, M02=R02*s2;
    float M10=R10*s0, M11=R11*s1, M12=R12*s2;
    float M20=R20*s0, M21=R21*s1, M22=R22*s2;
    float c00=M00*M00+M01*M01+M02*M02;
    float c01=M00*M10+M01*M11+M02*M12;
    float c02=M00*M20+M01*M21+M02*M22;
    float c11=M10*M10+M11*M11+M12*M12;
    float c12=M10*M20+M11*M21+M12*M22;
    float c22=M20*M20+M21*M21+M22*M22;

    const float fx=128.f, fy=128.f;
    float tz = depth;
    float txz = fminf(fmaxf(pv0/tz, -0.65f), 0.65f) * tz;
    float tyz = fminf(fmaxf(pv1/tz, -0.65f), 0.65f) * tz;
    float J00 = fx/tz,  J02 = -fx*txz/(tz*tz);
    float J11 = fy/tz,  J12 = -fy*tyz/(tz*tz);
    float T00=J00*view[0] + J02*view[2];
    float T01=J00*view[4] + J02*view[6];
    float T02=J00*view[8] + J02*view[10];
    float T10=J11*view[1] + J12*view[2];
    float T11=J11*view[5] + J12*view[6];
    float T12=J11*view[9] + J12*view[10];
    float u0 = T00*c00 + T01*c01 + T02*c02;
    float u1 = T00*c01 + T01*c11 + T02*c12;
    float u2 = T00*c02 + T01*c12 + T02*c22;
    float v0 = T10*c00 + T11*c01 + T12*c02;
    float v1 = T10*c01 + T11*c11 + T12*c12;
    float v2r= T10*c02 + T11*c12 + T12*c22;
    float a00 = u0*T00 + u1*T01 + u2*T02 + 0.3f;
    float a01 = u0*T10 + u1*T11 + u2*T12;
    float a11 = v0*T10 + v1*T11 + v2r*T12 + 0.3f;

    float det = a00*a11 - a01*a01;
    float dsafe = (det==0.f) ? 1.f : det;
    float inv = 1.f/dsafe;
    float con0 =  a11*inv, con1 = -a01*inv, con2 = a00*inv;
    float mid = 0.5f*(a00+a11);
    float lam1 = mid + sqrtf(fmaxf(0.1f, mid*mid - det));
    int irad = (int)ceilf(3.f*sqrtf(lam1));
    float pxc = ((pp0+1.f)*128.f - 1.f)*0.5f;
    float pyc = ((pp1+1.f)*128.f - 1.f)*0.5f;
    bool valid = (depth > 0.2f) && (det != 0.f);

    radii_out[n] = valid ? (float)irad : 0.f;
    order[r] = n;
    float* p = psort + 8*r;
    p[0]=pxc; p[1]=pyc; p[2]=con0; p[3]=con1; p[4]=con2;
    p[5]=opac[n]; p[6]=depth; p[7]= valid ? 1.f : 0.f;
    csort[4*r+0] = colors[3*n+0];
    csort[4*r+1] = colors[3*n+1];
    csort[4*r+2] = colors[3*n+2];
    csort[4*r+3] = 0.f;
}

// ---------------------------------------------------------------------------
// Kernel 2: G[m][o] = sum_k S[order[m]][k] * conv_w[o][k] via MFMA, operands
// read DIRECTLY from global (k-contiguous rows = fragment layout), fp32->bf16
// cvt in regs. grid (4 o-tiles, 16 m-tiles), 4 waves = 64m x 32o.
// [r10 kernel — exonerated: r10's failure was the idxl/wbuf ws overlap]
// ---------------------------------------------------------------------------
__global__ __launch_bounds__(256) void gemmG_kernel(const float* __restrict__ S,
                                                    const float* __restrict__ Wm,
                                                    const int* __restrict__ order,
                                                    __hip_bfloat16* __restrict__ Gvb)
{
    const int t    = threadIdx.x;
    const int lane = t & 63;
    const int wv   = t >> 6;
    const int m0   = blockIdx.y * 64;
    const int o0w  = blockIdx.x * 128 + wv * 32;
    const int lhi  = lane >> 4;
    const int llo  = lane & 15;

    int arow[4];
    #pragma unroll
    for (int mt = 0; mt < 4; ++mt) arow[mt] = order[m0 + mt*16 + llo] & (N_G - 1);

    f32x4 acc[4][2];
    #pragma unroll
    for (int mt = 0; mt < 4; ++mt)
        #pragma unroll
        for (int ot = 0; ot < 2; ++ot)
            acc[mt][ot] = (f32x4){0.f,0.f,0.f,0.f};

    for (int k0 = 0; k0 < F_DIM; k0 += 32) {
        const int kf = k0 + 8*lhi;
        bf16x8 af[4], bf[2];
        #pragma unroll
        for (int mt = 0; mt < 4; ++mt) {
            const float4* ap = reinterpret_cast<const float4*>(S + (size_t)arow[mt]*F_DIM + kf);
            float4 lo = ap[0], hi = ap[1];
            bf16x8 v;
            v[0]=__bfloat16_as_short(__float2bfloat16(lo.x));
            v[1]=__bfloat16_as_short(__float2bfloat16(lo.y));
            v[2]=__bfloat16_as_short(__float2bfloat16(lo.z));
            v[3]=__bfloat16_as_short(__float2bfloat16(lo.w));
            v[4]=__bfloat16_as_short(__float2bfloat16(hi.x));
            v[5]=__bfloat16_as_short(__float2bfloat16(hi.y));
            v[6]=__bfloat16_as_short(__float2bfloat16(hi.z));
            v[7]=__bfloat16_as_short(__float2bfloat16(hi.w));
            af[mt] = v;
        }
        #pragma unroll
        for (int ot = 0; ot < 2; ++ot) {
            const float4* bp = reinterpret_cast<const float4*>(Wm + (size_t)(o0w + ot*16 + llo)*F_DIM + kf);
            float4 lo = bp[0], hi = bp[1];
            bf16x8 v;
            v[0]=__bfloat16_as_short(__float2bfloat16(lo.x));
            v[1]=__bfloat16_as_short(__float2bfloat16(lo.y));
            v[2]=__bfloat16_as_short(__float2bfloat16(lo.z));
            v[3]=__bfloat16_as_short(__float2bfloat16(lo.w));
            v[4]=__bfloat16_as_short(__float2bfloat16(hi.x));
            v[5]=__bfloat16_as_short(__float2bfloat16(hi.y));
            v[6]=__bfloat16_as_short(__float2bfloat16(hi.z));
            v[7]=__bfloat16_as_short(__float2bfloat16(hi.w));
            bf[ot] = v;
        }
        #pragma unroll
        for (int mt = 0; mt < 4; ++mt)
            #pragma unroll
            for (int ot = 0; ot < 2; ++ot)
                acc[mt][ot] = __builtin_amdgcn_mfma_f32_16x16x32_bf16(
                    af[mt], bf[ot], acc[mt][ot], 0, 0, 0);
    }

    #pragma unroll
    for (int mt = 0; mt < 4; ++mt) {
        #pragma unroll
        for (int r = 0; r < 4; ++r) {
            int row = m0 + mt*16 + 4*lhi + r;
            #pragma unroll
            for (int ot = 0; ot < 2; ++ot) {
                int col = o0w + ot*16 + llo;
                Gvb[(size_t)row*O_DIM + col] = __float2bfloat16(acc[mt][ot][r]);
            }
        }
    }
}

// ---------------------------------------------------------------------------
// Kernel 3: fused alpha + featgemm  [r12-exact]
// ---------------------------------------------------------------------------
__global__ __launch_bounds__(1024) void alphafeat_kernel(
    const float* __restrict__ psort, const float* __restrict__ csort,
    const float* __restrict__ bg,
    const __hip_bfloat16* __restrict__ Gvb, const float* __restrict__ conv_b,
    float* __restrict__ out)
{
    __shared__ __align__(16) char uni[73728];           // GT region (phase B)
    float (*pg)[8]       = (float(*)[8])uni;            // [0,32768)
    float (*cs)[4]       = (float(*)[4])(uni + 32768);  // [32768,49152)
    float (*colbuf)[64][4] = (float(*)[64][4])(uni + 49152); // [49152,65536)
    float (*Pl)[64]      = (float(*)[64])(uni + 65536); // [65536,69632)
    short (*GT)[GT_PITCH] = (short(*)[GT_PITCH])uni;    // 512*72*2 = 73728

    __shared__ short WT[64][WT_PITCH];                  // 25.6 KB
    __shared__ float Tfl[64];
    __shared__ int   idx_lds[MAXG];
    __shared__ int   cntl_s[16];
    __shared__ int   cnt_tot;

    const int t    = threadIdx.x;
    const int c    = t >> 6;        // wave = chunk
    const int lane = t & 63;
    const int tile = blockIdx.x;
    const int hrow = tile >> 1;
    const int w0   = (tile & 1) * 64;

    {
        float4* pgv = reinterpret_cast<float4*>(&pg[0][0]);
        const float4* ps4 = reinterpret_cast<const float4*>(psort);
        pgv[t]        = ps4[t];
        pgv[t + 1024] = ps4[t + 1024];
        float4* csv = reinterpret_cast<float4*>(&cs[0][0]);
        csv[t] = reinterpret_cast<const float4*>(csort)[t];
        int* wtz = (int*)&WT[0][0];
        for (int i = t; i < 64*WT_PITCH/2; i += 1024) wtz[i] = 0;
        if (t < MAXG) idx_lds[t] = 0;
    }
    __syncthreads();

    const float gx = (float)(w0 + lane);
    const float gy = (float)hrow;

    // ---- pass 1: per-chunk transmittance + survivor count ----
    float pref = 1.f;
    int cnt = 0;
    for (int j = 0; j < 64; ++j) {
        int g = c*64 + j;
        float4 A = *reinterpret_cast<const float4*>(&pg[g][0]);
        float4 B = *reinterpret_cast<const float4*>(&pg[g][4]);
        float dx = A.x - gx, dy = A.y - gy;
        float pw = -0.5f*(A.z*dx*dx + B.x*dy*dy) - A.w*dx*dy;
        float al = fminf(0.99f, B.y*__expf(pw));
        bool keep = (pw <= 0.f) && (al >= (1.f/255.f)) && (B.w > 0.5f);
        float a = keep ? al : 0.f;
        float w = pref * a;
        pref *= 1.f - a;
        cnt += (__ballot(w > 1e-12f) != 0ull) ? 1 : 0;
    }
    Pl[c][lane] = pref;
    if (lane == 0) cntl_s[c] = cnt;
    __syncthreads();

    int base = 0;
    float cp = 1.f;
    for (int cc = 0; cc < c; ++cc) {
        base += cntl_s[cc];
        cp *= Pl[cc][lane];
    }
    if (c == 15) {
        Tfl[lane] = cp * Pl[15][lane];
        if (lane == 0) {
            int tot = base + cntl_s[15];
            cnt_tot = (tot < MAXG) ? tot : MAXG;
        }
    }

    // ---- pass 2: weights -> WT LDS (transposed layout), color accum ----
    float pref2 = 1.f;
    int slot = base;
    float col0 = 0.f, col1 = 0.f, col2 = 0.f;
    for (int j = 0; j < 64; ++j) {
        int g = c*64 + j;
        float4 A = *reinterpret_cast<const float4*>(&pg[g][0]);
        float4 B = *reinterpret_cast<const float4*>(&pg[g][4]);
        float dx = A.x - gx, dy = A.y - gy;
        float pw = -0.5f*(A.z*dx*dx + B.x*dy*dy) - A.w*dx*dy;
        float al = fminf(0.99f, B.y*__expf(pw));
        bool keep = (pw <= 0.f) && (al >= (1.f/255.f)) && (B.w > 0.5f);
        float a = keep ? al : 0.f;
        float w = pref2 * a;
        pref2 *= 1.f - a;
        if (__ballot(w > 1e-12f) != 0ull) {
            float wfin = w * cp;
            if (slot < MAXG) {
                WT[lane][slot] = __bfloat16_as_short(__float2bfloat16(wfin));
                if (lane == 0) idx_lds[slot] = g;
            }
            float4 cv = *reinterpret_cast<const float4*>(&cs[g][0]);
            col0 += wfin*cv.x; col1 += wfin*cv.y; col2 += wfin*cv.z;
            ++slot;
        }
    }

    colbuf[c][lane][0] = col0; colbuf[c][lane][1] = col1; colbuf[c][lane][2] = col2;
    __syncthreads();

    if (t < 64) {
        float r = 0.f, g = 0.f, b = 0.f;
        #pragma unroll
        for (int k = 0; k < 16; ++k) {
            r += colbuf[k][t][0]; g += colbuf[k][t][1]; b += colbuf[k][t][2];
        }
        float Tf = Tfl[t];
        int pix = hrow*W_IMG + w0 + t;
        out[0*PIX + pix] = r + Tf*bg[0];
        out[1*PIX + pix] = g + Tf*bg[1];
        out[2*PIX + pix] = b + Tf*bg[2];
    }
    __syncthreads();    // colbuf/pg/cs dead; WT/idx/cnt_tot visible

    // ---- featgemm phase: 16 waves x 32 o ----
    int scnt = cnt_tot;
    scnt = (scnt < 0) ? 0 : ((scnt > MAXG) ? MAXG : scnt);
    const short* gvs = (const short*)Gvb;

    f32x4 acc[2][4];
    #pragma unroll
    for (int i = 0; i < 2; ++i)
        #pragma unroll
        for (int j = 0; j < 4; ++j)
            acc[i][j] = (f32x4){0.f,0.f,0.f,0.f};

    const int nchunk = (scnt + 63) >> 6;
    for (int cc = 0; cc < nchunk; ++cc) {
        const int kbase = cc*64;
        {
            const int o = t & 511;
            const int half = t >> 9;
            #pragma unroll
            for (int b = 0; b < 4; ++b) {
                bf16x8 s;
                #pragma unroll
                for (int j = 0; j < 8; ++j) {
                    int k = kbase + half*32 + b*8 + j;
                    s[j] = (k < scnt) ? gvs[(size_t)idx_lds[k]*O_DIM + o] : (short)0;
                }
                *(bf16x8*)&GT[o][half*32 + b*8] = s;
            }
        }
        __syncthreads();

        #pragma unroll
        for (int ks = 0; ks < 2; ++ks) {
            const int kf = 8*(lane>>4);
            bf16x8 bfr[4];
            #pragma unroll
            for (int pt = 0; pt < 4; ++pt)
                bfr[pt] = *(const bf16x8*)&WT[pt*16 + (lane&15)][kbase + ks*32 + kf];
            #pragma unroll
            for (int ot = 0; ot < 2; ++ot) {
                bf16x8 af = *(const bf16x8*)&GT[c*32 + ot*16 + (lane&15)][ks*32 + kf];
                #pragma unroll
                for (int pt = 0; pt < 4; ++pt)
                    acc[ot][pt] = __builtin_amdgcn_mfma_f32_16x16x32_bf16(
                        af, bfr[pt], acc[ot][pt], 0, 0, 0);
            }
        }
        __syncthreads();
    }

    const int pixbase = hrow*W_IMG + w0;
    #pragma unroll
    for (int ot = 0; ot < 2; ++ot) {
        #pragma unroll
        for (int r = 0; r < 4; ++r) {
            int o = c*32 + ot*16 + 4*(lane>>4) + r;
            float cb = conv_b[o];
            #pragma unroll
            for (int pt = 0; pt < 4; ++pt) {
                out[FEAT_OFF + (size_t)o*PIX + pixbase + pt*16 + (lane&15)]
                    = acc[ot][pt][r] + cb;
            }
        }
    }
}

// ---------------------------------------------------------------------------
extern "C" void kernel_launch(void* const* d_in, const int* in_sizes, int n_in,
                              void* d_out, int out_size, void* d_ws, size_t ws_size,
                              hipStream_t stream)
{
    const float* means  = (const float*)d_in[0];
    const float* opac   = (const float*)d_in[2];
    const float* colors = (const float*)d_in[3];
    const float* sem    = (const float*)d_in[4];
    const float* scales = (const float*)d_in[5];
    const float* rots   = (const float*)d_in[6];
    const float* view   = (const float*)d_in[7];
    const float* proj   = (const float*)d_in[8];
    const float* bg     = (const float*)d_in[9];
    const float* conv_w = (const float*)d_in[11];
    const float* conv_b = (const float*)d_in[12];
    float* out = (float*)d_out;

    // --- workspace layout (f32 slots; sizes audited in BYTES) ---
    // psort: [0, 8192)                 1024*8 f32      = 32768 B
    // csort: [8192, 12288)             1024*4 f32      = 16384 B
    // order: [12288, 13312)            1024 int        =  4096 B
    // Gvb:   [16384, 278528)           1024*512 bf16   = 1,048,576 B = 262,144 f32 slots
    float* wsf   = (float*)d_ws;
    float* psort = wsf;
    float* csort = wsf + 8192;
    int*   order = (int*)(wsf + 12288);
    __hip_bfloat16* Gvb = (__hip_bfloat16*)(wsf + 16384);

    float* radii_out = out + RAD_OFF;

    preprank_kernel<<<4, 256, 0, stream>>>(means, opac, colors, scales, rots,
                                           view, proj, order, psort, csort,
                                           radii_out);
    gemmG_kernel<<<dim3(4,16), 256, 0, stream>>>(sem, conv_w, order, Gvb);
    alphafeat_kernel<<<256, 1024, 0, stream>>>(psort, csort, bg, Gvb, conv_b, out);
}

// Round 14
// 94.515 us; speedup vs baseline: 2.0984x; 1.1689x over previous
//
#include <hip/hip_runtime.h>
#include <hip/hip_bf16.h>
#include <math.h>

#define H_IMG 128
#define W_IMG 128
#define N_G   1024
#define F_DIM 512
#define O_DIM 512
#define PIX   (H_IMG*W_IMG)        // 16384
#define FEAT_OFF 49152             // 3*PIX
#define RAD_OFF  (49152 + 512*16384)
#define MAXG  192                  // per-tile survivor cap (validated r2-r13)
#define WT_PITCH 200               // shorts; 400B row stride (16B-aligned)
#define GT_PITCH 72                // shorts; 144B row stride (16B-aligned)

typedef __attribute__((ext_vector_type(8))) short bf16x8;
typedef __attribute__((ext_vector_type(4))) float f32x4;

// ---------------------------------------------------------------------------
// Kernel 1: fused prep + rank + pack  [r12-exact]
// ---------------------------------------------------------------------------
__global__ __launch_bounds__(256) void preprank_kernel(
    const float* __restrict__ means,
    const float* __restrict__ opac,
    const float* __restrict__ colors,
    const float* __restrict__ scales,
    const float* __restrict__ rots,
    const float* __restrict__ view,
    const float* __restrict__ proj,
    int* __restrict__ order,
    float* __restrict__ psort,
    float* __restrict__ csort,
    float* __restrict__ radii_out)
{
    __shared__ float d[N_G];
    const int t = threadIdx.x;
    const float v2 = view[2], v6 = view[6], v10 = view[10], v14 = view[14];
    for (int i = t; i < N_G; i += 256)
        d[i] = means[3*i]*v2 + means[3*i+1]*v6 + means[3*i+2]*v10 + v14;
    __syncthreads();

    const int n = blockIdx.x*256 + t;
    const float depth = d[n];

    int r = 0;
    for (int m = 0; m < N_G; ++m) {
        float dm = d[m];
        r += (dm < depth) || (dm == depth && m < n);
    }

    float x = means[3*n], y = means[3*n+1], z = means[3*n+2];
    float pv0 = x*view[0] + y*view[4] + z*view[8]  + view[12];
    float pv1 = x*view[1] + y*view[5] + z*view[9]  + view[13];
    float ph0 = x*proj[0] + y*proj[4] + z*proj[8]  + proj[12];
    float ph1 = x*proj[1] + y*proj[5] + z*proj[9]  + proj[13];
    float phw = x*proj[3] + y*proj[7] + z*proj[11] + proj[15];
    float denom = phw + 1e-7f;
    float pp0 = ph0/denom, pp1 = ph1/denom;

    float qr=rots[4*n], qx=rots[4*n+1], qy=rots[4*n+2], qz=rots[4*n+3];
    float qn = sqrtf(qr*qr+qx*qx+qy*qy+qz*qz);
    qr/=qn; qx/=qn; qy/=qn; qz/=qn;
    float R00=1.f-2.f*(qy*qy+qz*qz), R01=2.f*(qx*qy-qr*qz), R02=2.f*(qx*qz+qr*qy);
    float R10=2.f*(qx*qy+qr*qz), R11=1.f-2.f*(qx*qx+qz*qz), R12=2.f*(qy*qz-qr*qx);
    float R20=2.f*(qx*qz-qr*qy), R21=2.f*(qy*qz+qr*qx), R22=1.f-2.f*(qx*qx+qy*qy);
    float s0=scales[3*n], s1=scales[3*n+1], s2=scales[3*n+2];
    float M00=R00*s0, M01=R01*s1, M02=R02*s2;
    float M10=R10*s0, M11=R11*s1, M12=R12*s2;
    float M20=R20*s0, M21=R21*s1, M22=R22*s2;
    float c00=M00*M00+M01*M01+M02*M02;
    float c01=M00*M10+M01*M11+M02*M12;
    float c02=M00*M20+M01*M21+M02*M22;
    float c11=M10*M10+M11*M11+M12*M12;
    float c12=M10*M20+M11*M21+M12*M22;
    float c22=M20*M20+M21*M21+M22*M22;

    const float fx=128.f, fy=128.f;
    float tz = depth;
    float txz = fminf(fmaxf(pv0/tz, -0.65f), 0.65f) * tz;
    float tyz = fminf(fmaxf(pv1/tz, -0.65f), 0.65f) * tz;
    float J00 = fx/tz,  J02 = -fx*txz/(tz*tz);
    float J11 = fy/tz,  J12 = -fy*tyz/(tz*tz);
    float T00=J00*view[0] + J02*view[2];
    float T01=J00*view[4] + J02*view[6];
    float T02=J00*view[8] + J02*view[10];
    float T10=J11*view[1] + J12*view[2];
    float T11=J11*view[5] + J12*view[6];
    float T12=J11*view[9] + J12*view[10];
    float u0 = T00*c00 + T01*c01 + T02*c02;
    float u1 = T00*c01 + T01*c11 + T02*c12;
    float u2 = T00*c02 + T01*c12 + T02*c22;
    float v0 = T10*c00 + T11*c01 + T12*c02;
    float v1 = T10*c01 + T11*c11 + T12*c12;
    float v2r= T10*c02 + T11*c12 + T12*c22;
    float a00 = u0*T00 + u1*T01 + u2*T02 + 0.3f;
    float a01 = u0*T10 + u1*T11 + u2*T12;
    float a11 = v0*T10 + v1*T11 + v2r*T12 + 0.3f;

    float det = a00*a11 - a01*a01;
    float dsafe = (det==0.f) ? 1.f : det;
    float inv = 1.f/dsafe;
    float con0 =  a11*inv, con1 = -a01*inv, con2 = a00*inv;
    float mid = 0.5f*(a00+a11);
    float lam1 = mid + sqrtf(fmaxf(0.1f, mid*mid - det));
    int irad = (int)ceilf(3.f*sqrtf(lam1));
    float pxc = ((pp0+1.f)*128.f - 1.f)*0.5f;
    float pyc = ((pp1+1.f)*128.f - 1.f)*0.5f;
    bool valid = (depth > 0.2f) && (det != 0.f);

    radii_out[n] = valid ? (float)irad : 0.f;
    order[r] = n;
    float* p = psort + 8*r;
    p[0]=pxc; p[1]=pyc; p[2]=con0; p[3]=con1; p[4]=con2;
    p[5]=opac[n]; p[6]=depth; p[7]= valid ? 1.f : 0.f;
    csort[4*r+0] = colors[3*n+0];
    csort[4*r+1] = colors[3*n+1];
    csort[4*r+2] = colors[3*n+2];
    csort[4*r+3] = 0.f;
}

// ---------------------------------------------------------------------------
// Kernel 2: G[m][o] = sum_k S[order[m]][k] * conv_w[o][k] via MFMA,
// direct-from-global operands. grid (16 o-tiles of 32, 16 m-tiles of 64),
// 256 blocks x 4 waves; each wave: 16m x 32o, full K. [r13-passing math]
// ---------------------------------------------------------------------------
__global__ __launch_bounds__(256) void gemmG_kernel(const float* __restrict__ S,
                                                    const float* __restrict__ Wm,
                                                    const int* __restrict__ order,
                                                    __hip_bfloat16* __restrict__ Gvb)
{
    const int t    = threadIdx.x;
    const int lane = t & 63;
    const int wv   = t >> 6;
    const int m0   = blockIdx.y * 64 + wv * 16;   // wave's 16 m-rows
    const int o0   = blockIdx.x * 32;             // block's 32 o-cols
    const int lhi  = lane >> 4;
    const int llo  = lane & 15;

    const int arow = order[m0 + llo] & (N_G - 1);

    f32x4 acc[2];
    acc[0] = (f32x4){0.f,0.f,0.f,0.f};
    acc[1] = (f32x4){0.f,0.f,0.f,0.f};

    #pragma unroll 2
    for (int k0 = 0; k0 < F_DIM; k0 += 32) {
        const int kf = k0 + 8*lhi;
        bf16x8 af, bf[2];
        {
            const float4* ap = reinterpret_cast<const float4*>(S + (size_t)arow*F_DIM + kf);
            float4 lo = ap[0], hi = ap[1];
            bf16x8 v;
            v[0]=__bfloat16_as_short(__float2bfloat16(lo.x));
            v[1]=__bfloat16_as_short(__float2bfloat16(lo.y));
            v[2]=__bfloat16_as_short(__float2bfloat16(lo.z));
            v[3]=__bfloat16_as_short(__float2bfloat16(lo.w));
            v[4]=__bfloat16_as_short(__float2bfloat16(hi.x));
            v[5]=__bfloat16_as_short(__float2bfloat16(hi.y));
            v[6]=__bfloat16_as_short(__float2bfloat16(hi.z));
            v[7]=__bfloat16_as_short(__float2bfloat16(hi.w));
            af = v;
        }
        #pragma unroll
        for (int ot = 0; ot < 2; ++ot) {
            const float4* bp = reinterpret_cast<const float4*>(Wm + (size_t)(o0 + ot*16 + llo)*F_DIM + kf);
            float4 lo = bp[0], hi = bp[1];
            bf16x8 v;
            v[0]=__bfloat16_as_short(__float2bfloat16(lo.x));
            v[1]=__bfloat16_as_short(__float2bfloat16(lo.y));
            v[2]=__bfloat16_as_short(__float2bfloat16(lo.z));
            v[3]=__bfloat16_as_short(__float2bfloat16(lo.w));
            v[4]=__bfloat16_as_short(__float2bfloat16(hi.x));
            v[5]=__bfloat16_as_short(__float2bfloat16(hi.y));
            v[6]=__bfloat16_as_short(__float2bfloat16(hi.z));
            v[7]=__bfloat16_as_short(__float2bfloat16(hi.w));
            bf[ot] = v;
        }
        acc[0] = __builtin_amdgcn_mfma_f32_16x16x32_bf16(af, bf[0], acc[0], 0, 0, 0);
        acc[1] = __builtin_amdgcn_mfma_f32_16x16x32_bf16(af, bf[1], acc[1], 0, 0, 0);
    }

    #pragma unroll
    for (int r = 0; r < 4; ++r) {
        int row = m0 + 4*lhi + r;
        #pragma unroll
        for (int ot = 0; ot < 2; ++ot) {
            int col = o0 + ot*16 + llo;
            Gvb[(size_t)row*O_DIM + col] = __float2bfloat16(acc[ot][r]);
        }
    }
}

// ---------------------------------------------------------------------------
// Kernel 3: fused alpha + featgemm  [r12 core + register-prefetch alpha loops]
// ---------------------------------------------------------------------------
__global__ __launch_bounds__(1024) void alphafeat_kernel(
    const float* __restrict__ psort, const float* __restrict__ csort,
    const float* __restrict__ bg,
    const __hip_bfloat16* __restrict__ Gvb, const float* __restrict__ conv_b,
    float* __restrict__ out)
{
    __shared__ __align__(16) char uni[73728];           // GT region (phase B)
    float (*pg)[8]       = (float(*)[8])uni;            // [0,32768)
    float (*cs)[4]       = (float(*)[4])(uni + 32768);  // [32768,49152)
    float (*colbuf)[64][4] = (float(*)[64][4])(uni + 49152); // [49152,65536)
    float (*Pl)[64]      = (float(*)[64])(uni + 65536); // [65536,69632)
    short (*GT)[GT_PITCH] = (short(*)[GT_PITCH])uni;    // 512*72*2 = 73728

    __shared__ short WT[64][WT_PITCH];                  // 25.6 KB
    __shared__ float Tfl[64];
    __shared__ int   idx_lds[MAXG];
    __shared__ int   cntl_s[16];
    __shared__ int   cnt_tot;

    const int t    = threadIdx.x;
    const int c    = t >> 6;        // wave = chunk
    const int lane = t & 63;
    const int tile = blockIdx.x;
    const int hrow = tile >> 1;
    const int w0   = (tile & 1) * 64;

    {
        float4* pgv = reinterpret_cast<float4*>(&pg[0][0]);
        const float4* ps4 = reinterpret_cast<const float4*>(psort);
        pgv[t]        = ps4[t];
        pgv[t + 1024] = ps4[t + 1024];
        float4* csv = reinterpret_cast<float4*>(&cs[0][0]);
        csv[t] = reinterpret_cast<const float4*>(csort)[t];
        int* wtz = (int*)&WT[0][0];
        for (int i = t; i < 64*WT_PITCH/2; i += 1024) wtz[i] = 0;
        if (t < MAXG) idx_lds[t] = 0;
    }
    __syncthreads();

    const float gx = (float)(w0 + lane);
    const float gy = (float)hrow;
    const float4* pgw = reinterpret_cast<const float4*>(&pg[c*64][0]);

    // ---- pass 1: per-chunk transmittance + survivor count (prefetched) ----
    float pref = 1.f;
    int cnt = 0;
    {
        float4 A = pgw[0], B = pgw[1];
        for (int j = 0; j < 64; ++j) {
            float4 An, Bn;
            if (j < 63) { An = pgw[2*j+2]; Bn = pgw[2*j+3]; }
            float dx = A.x - gx, dy = A.y - gy;
            float pw = -0.5f*(A.z*dx*dx + B.x*dy*dy) - A.w*dx*dy;
            float al = fminf(0.99f, B.y*__expf(pw));
            bool keep = (pw <= 0.f) && (al >= (1.f/255.f)) && (B.w > 0.5f);
            float a = keep ? al : 0.f;
            float w = pref * a;
            pref *= 1.f - a;
            cnt += (__ballot(w > 1e-12f) != 0ull) ? 1 : 0;
            A = An; B = Bn;
        }
    }
    Pl[c][lane] = pref;
    if (lane == 0) cntl_s[c] = cnt;
    __syncthreads();

    int base = 0;
    float cp = 1.f;
    for (int cc = 0; cc < c; ++cc) {
        base += cntl_s[cc];
        cp *= Pl[cc][lane];
    }
    if (c == 15) {
        Tfl[lane] = cp * Pl[15][lane];
        if (lane == 0) {
            int tot = base + cntl_s[15];
            cnt_tot = (tot < MAXG) ? tot : MAXG;
        }
    }

    // ---- pass 2: weights -> WT LDS, color accum (prefetched) ----
    float pref2 = 1.f;
    int slot = base;
    float col0 = 0.f, col1 = 0.f, col2 = 0.f;
    {
        float4 A = pgw[0], B = pgw[1];
        for (int j = 0; j < 64; ++j) {
            float4 An, Bn;
            if (j < 63) { An = pgw[2*j+2]; Bn = pgw[2*j+3]; }
            float dx = A.x - gx, dy = A.y - gy;
            float pw = -0.5f*(A.z*dx*dx + B.x*dy*dy) - A.w*dx*dy;
            float al = fminf(0.99f, B.y*__expf(pw));
            bool keep = (pw <= 0.f) && (al >= (1.f/255.f)) && (B.w > 0.5f);
            float a = keep ? al : 0.f;
            float w = pref2 * a;
            pref2 *= 1.f - a;
            if (__ballot(w > 1e-12f) != 0ull) {
                float wfin = w * cp;
                if (slot < MAXG) {
                    WT[lane][slot] = __bfloat16_as_short(__float2bfloat16(wfin));
                    if (lane == 0) idx_lds[slot] = c*64 + j;
                }
                float4 cv = *reinterpret_cast<const float4*>(&cs[c*64 + j][0]);
                col0 += wfin*cv.x; col1 += wfin*cv.y; col2 += wfin*cv.z;
                ++slot;
            }
            A = An; B = Bn;
        }
    }

    colbuf[c][lane][0] = col0; colbuf[c][lane][1] = col1; colbuf[c][lane][2] = col2;
    __syncthreads();

    if (t < 64) {
        float r = 0.f, g = 0.f, b = 0.f;
        #pragma unroll
        for (int k = 0; k < 16; ++k) {
            r += colbuf[k][t][0]; g += colbuf[k][t][1]; b += colbuf[k][t][2];
        }
        float Tf = Tfl[t];
        int pix = hrow*W_IMG + w0 + t;
        out[0*PIX + pix] = r + Tf*bg[0];
        out[1*PIX + pix] = g + Tf*bg[1];
        out[2*PIX + pix] = b + Tf*bg[2];
    }
    __syncthreads();    // colbuf/pg/cs dead; WT/idx/cnt_tot visible

    // ---- featgemm phase: 16 waves x 32 o ----
    int scnt = cnt_tot;
    scnt = (scnt < 0) ? 0 : ((scnt > MAXG) ? MAXG : scnt);
    const short* gvs = (const short*)Gvb;

    f32x4 acc[2][4];
    #pragma unroll
    for (int i = 0; i < 2; ++i)
        #pragma unroll
        for (int j = 0; j < 4; ++j)
            acc[i][j] = (f32x4){0.f,0.f,0.f,0.f};

    const int nchunk = (scnt + 63) >> 6;
    for (int cc = 0; cc < nchunk; ++cc) {
        const int kbase = cc*64;
        {
            const int o = t & 511;
            const int half = t >> 9;
            #pragma unroll
            for (int b = 0; b < 4; ++b) {
                bf16x8 s;
                #pragma unroll
                for (int j = 0; j < 8; ++j) {
                    int k = kbase + half*32 + b*8 + j;
                    s[j] = (k < scnt) ? gvs[(size_t)idx_lds[k]*O_DIM + o] : (short)0;
                }
                *(bf16x8*)&GT[o][half*32 + b*8] = s;
            }
        }
        __syncthreads();

        #pragma unroll
        for (int ks = 0; ks < 2; ++ks) {
            const int kf = 8*(lane>>4);
            bf16x8 bfr[4];
            #pragma unroll
            for (int pt = 0; pt < 4; ++pt)
                bfr[pt] = *(const bf16x8*)&WT[pt*16 + (lane&15)][kbase + ks*32 + kf];
            #pragma unroll
            for (int ot = 0; ot < 2; ++ot) {
                bf16x8 af = *(const bf16x8*)&GT[c*32 + ot*16 + (lane&15)][ks*32 + kf];
                #pragma unroll
                for (int pt = 0; pt < 4; ++pt)
                    acc[ot][pt] = __builtin_amdgcn_mfma_f32_16x16x32_bf16(
                        af, bfr[pt], acc[ot][pt], 0, 0, 0);
            }
        }
        __syncthreads();
    }

    const int pixbase = hrow*W_IMG + w0;
    #pragma unroll
    for (int ot = 0; ot < 2; ++ot) {
        #pragma unroll
        for (int r = 0; r < 4; ++r) {
            int o = c*32 + ot*16 + 4*(lane>>4) + r;
            float cb = conv_b[o];
            #pragma unroll
            for (int pt = 0; pt < 4; ++pt) {
                out[FEAT_OFF + (size_t)o*PIX + pixbase + pt*16 + (lane&15)]
                    = acc[ot][pt][r] + cb;
            }
        }
    }
}

// ---------------------------------------------------------------------------
extern "C" void kernel_launch(void* const* d_in, const int* in_sizes, int n_in,
                              void* d_out, int out_size, void* d_ws, size_t ws_size,
                              hipStream_t stream)
{
    const float* means  = (const float*)d_in[0];
    const float* opac   = (const float*)d_in[2];
    const float* colors = (const float*)d_in[3];
    const float* sem    = (const float*)d_in[4];
    const float* scales = (const float*)d_in[5];
    const float* rots   = (const float*)d_in[6];
    const float* view   = (const float*)d_in[7];
    const float* proj   = (const float*)d_in[8];
    const float* bg     = (const float*)d_in[9];
    const float* conv_w = (const float*)d_in[11];
    const float* conv_b = (const float*)d_in[12];
    float* out = (float*)d_out;

    // --- workspace layout (f32 slots; sizes audited in BYTES) ---
    // psort: [0, 8192)                 1024*8 f32      = 32768 B
    // csort: [8192, 12288)             1024*4 f32      = 16384 B
    // order: [12288, 13312)            1024 int        =  4096 B
    // Gvb:   [16384, 278528)           1024*512 bf16   = 1,048,576 B = 262,144 f32 slots
    float* wsf   = (float*)d_ws;
    float* psort = wsf;
    float* csort = wsf + 8192;
    int*   order = (int*)(wsf + 12288);
    __hip_bfloat16* Gvb = (__hip_bfloat16*)(wsf + 16384);

    float* radii_out = out + RAD_OFF;

    preprank_kernel<<<4, 256, 0, stream>>>(means, opac, colors, scales, rots,
                                           view, proj, order, psort, csort,
                                           radii_out);
    gemmG_kernel<<<dim3(16,16), 256, 0, stream>>>(sem, conv_w, order, Gvb);
    alphafeat_kernel<<<256, 1024, 0, stream>>>(psort, csort, bg, Gvb, conv_b, out);
}

// Round 15
// 89.760 us; speedup vs baseline: 2.2095x; 1.0530x over previous
//
#include <hip/hip_runtime.h>
#include <hip/hip_bf16.h>
#include <math.h>

#define H_IMG 128
#define W_IMG 128
#define N_G   1024
#define F_DIM 512
#define O_DIM 512
#define PIX   (H_IMG*W_IMG)        // 16384
#define FEAT_OFF 49152             // 3*PIX
#define RAD_OFF  (49152 + 512*16384)
#define MAXG  192                  // per-tile survivor cap (validated r2-r14)
#define WT_PITCH 200               // shorts; 400B row stride (16B-aligned)
#define GT_PITCH 72                // shorts; 144B row stride (16B-aligned)

typedef __attribute__((ext_vector_type(8))) short bf16x8;
typedef __attribute__((ext_vector_type(4))) float f32x4;

// ---------------------------------------------------------------------------
// Kernel 1: fused prep + rank + pack + cull-radius emit
// ---------------------------------------------------------------------------
__global__ __launch_bounds__(256) void preprank_kernel(
    const float* __restrict__ means,
    const float* __restrict__ opac,
    const float* __restrict__ colors,
    const float* __restrict__ scales,
    const float* __restrict__ rots,
    const float* __restrict__ view,
    const float* __restrict__ proj,
    int* __restrict__ order,
    float* __restrict__ psort,
    float* __restrict__ csort,
    float* __restrict__ rb,
    float* __restrict__ radii_out)
{
    __shared__ float d[N_G];
    const int t = threadIdx.x;
    const float v2 = view[2], v6 = view[6], v10 = view[10], v14 = view[14];
    for (int i = t; i < N_G; i += 256)
        d[i] = means[3*i]*v2 + means[3*i+1]*v6 + means[3*i+2]*v10 + v14;
    __syncthreads();

    const int n = blockIdx.x*256 + t;
    const float depth = d[n];

    int r = 0;
    for (int m = 0; m < N_G; ++m) {
        float dm = d[m];
        r += (dm < depth) || (dm == depth && m < n);
    }

    float x = means[3*n], y = means[3*n+1], z = means[3*n+2];
    float pv0 = x*view[0] + y*view[4] + z*view[8]  + view[12];
    float pv1 = x*view[1] + y*view[5] + z*view[9]  + view[13];
    float ph0 = x*proj[0] + y*proj[4] + z*proj[8]  + proj[12];
    float ph1 = x*proj[1] + y*proj[5] + z*proj[9]  + proj[13];
    float phw = x*proj[3] + y*proj[7] + z*proj[11] + proj[15];
    float denom = phw + 1e-7f;
    float pp0 = ph0/denom, pp1 = ph1/denom;

    float qr=rots[4*n], qx=rots[4*n+1], qy=rots[4*n+2], qz=rots[4*n+3];
    float qn = sqrtf(qr*qr+qx*qx+qy*qy+qz*qz);
    qr/=qn; qx/=qn; qy/=qn; qz/=qn;
    float R00=1.f-2.f*(qy*qy+qz*qz), R01=2.f*(qx*qy-qr*qz), R02=2.f*(qx*qz+qr*qy);
    float R10=2.f*(qx*qy+qr*qz), R11=1.f-2.f*(qx*qx+qz*qz), R12=2.f*(qy*qz-qr*qx);
    float R20=2.f*(qx*qz-qr*qy), R21=2.f*(qy*qz+qr*qx), R22=1.f-2.f*(qx*qx+qy*qy);
    float s0=scales[3*n], s1=scales[3*n+1], s2=scales[3*n+2];
    float M00=R00*s0, M01=R01*s1, M02=R02*s2;
    float M10=R10*s0, M11=R11*s1, M12=R12*s2;
    float M20=R20*s0, M21=R21*s1, M22=R22*s2;
    float c00=M00*M00+M01*M01+M02*M02;
    float c01=M00*M10+M01*M11+M02*M12;
    float c02=M00*M20+M01*M21+M02*M22;
    float c11=M10*M10+M11*M11+M12*M12;
    float c12=M10*M20+M11*M21+M12*M22;
    float c22=M20*M20+M21*M21+M22*M22;

    const float fx=128.f, fy=128.f;
    float tz = depth;
    float txz = fminf(fmaxf(pv0/tz, -0.65f), 0.65f) * tz;
    float tyz = fminf(fmaxf(pv1/tz, -0.65f), 0.65f) * tz;
    float J00 = fx/tz,  J02 = -fx*txz/(tz*tz);
    float J11 = fy/tz,  J12 = -fy*tyz/(tz*tz);
    float T00=J00*view[0] + J02*view[2];
    float T01=J00*view[4] + J02*view[6];
    float T02=J00*view[8] + J02*view[10];
    float T10=J11*view[1] + J12*view[2];
    float T11=J11*view[5] + J12*view[6];
    float T12=J11*view[9] + J12*view[10];
    float u0 = T00*c00 + T01*c01 + T02*c02;
    float u1 = T00*c01 + T01*c11 + T02*c12;
    float u2 = T00*c02 + T01*c12 + T02*c22;
    float v0 = T10*c00 + T11*c01 + T12*c02;
    float v1 = T10*c01 + T11*c11 + T12*c12;
    float v2r= T10*c02 + T11*c12 + T12*c22;
    float a00 = u0*T00 + u1*T01 + u2*T02 + 0.3f;
    float a01 = u0*T10 + u1*T11 + u2*T12;
    float a11 = v0*T10 + v1*T11 + v2r*T12 + 0.3f;

    float det = a00*a11 - a01*a01;
    float dsafe = (det==0.f) ? 1.f : det;
    float inv = 1.f/dsafe;
    float con0 =  a11*inv, con1 = -a01*inv, con2 = a00*inv;
    float mid = 0.5f*(a00+a11);
    float lam1 = mid + sqrtf(fmaxf(0.1f, mid*mid - det));
    int irad = (int)ceilf(3.f*sqrtf(lam1));
    float pxc = ((pp0+1.f)*128.f - 1.f)*0.5f;
    float pyc = ((pp1+1.f)*128.f - 1.f)*0.5f;
    bool valid = (depth > 0.2f) && (det != 0.f);

    radii_out[n] = valid ? (float)irad : 0.f;
    order[r] = n;
    float* p = psort + 8*r;
    p[0]=pxc; p[1]=pyc; p[2]=con0; p[3]=con1; p[4]=con2;
    p[5]=opac[n]; p[6]=depth; p[7]= valid ? 1.f : 0.f;
    csort[4*r+0] = colors[3*n+0];
    csort[4*r+1] = colors[3*n+1];
    csort[4*r+2] = colors[3*n+2];
    csort[4*r+3] = 0.f;

    // cull radii: keep region is inside ellipse 0.5 d^T conic d <= tau,
    // tau = ln(255*opac); axis extents sqrt(2 tau a00/a11). Invalid -> -1.
    float op = opac[n];
    float tau = logf(255.f * op);
    bool active = valid && (tau > 0.f);
    float rx = active ? (sqrtf(2.f*tau*a00) + 0.01f) : -1.f;
    float ry = active ? (sqrtf(2.f*tau*a11) + 0.01f) : -1.f;
    rb[2*r+0] = rx;
    rb[2*r+1] = ry;
}

// ---------------------------------------------------------------------------
// Kernel 2: G[m][o] via MFMA, direct-from-global  [r14-exact, 256 blocks]
// ---------------------------------------------------------------------------
__global__ __launch_bounds__(256) void gemmG_kernel(const float* __restrict__ S,
                                                    const float* __restrict__ Wm,
                                                    const int* __restrict__ order,
                                                    __hip_bfloat16* __restrict__ Gvb)
{
    const int t    = threadIdx.x;
    const int lane = t & 63;
    const int wv   = t >> 6;
    const int m0   = blockIdx.y * 64 + wv * 16;
    const int o0   = blockIdx.x * 32;
    const int lhi  = lane >> 4;
    const int llo  = lane & 15;

    const int arow = order[m0 + llo] & (N_G - 1);

    f32x4 acc[2];
    acc[0] = (f32x4){0.f,0.f,0.f,0.f};
    acc[1] = (f32x4){0.f,0.f,0.f,0.f};

    #pragma unroll 2
    for (int k0 = 0; k0 < F_DIM; k0 += 32) {
        const int kf = k0 + 8*lhi;
        bf16x8 af, bf[2];
        {
            const float4* ap = reinterpret_cast<const float4*>(S + (size_t)arow*F_DIM + kf);
            float4 lo = ap[0], hi = ap[1];
            bf16x8 v;
            v[0]=__bfloat16_as_short(__float2bfloat16(lo.x));
            v[1]=__bfloat16_as_short(__float2bfloat16(lo.y));
            v[2]=__bfloat16_as_short(__float2bfloat16(lo.z));
            v[3]=__bfloat16_as_short(__float2bfloat16(lo.w));
            v[4]=__bfloat16_as_short(__float2bfloat16(hi.x));
            v[5]=__bfloat16_as_short(__float2bfloat16(hi.y));
            v[6]=__bfloat16_as_short(__float2bfloat16(hi.z));
            v[7]=__bfloat16_as_short(__float2bfloat16(hi.w));
            af = v;
        }
        #pragma unroll
        for (int ot = 0; ot < 2; ++ot) {
            const float4* bp = reinterpret_cast<const float4*>(Wm + (size_t)(o0 + ot*16 + llo)*F_DIM + kf);
            float4 lo = bp[0], hi = bp[1];
            bf16x8 v;
            v[0]=__bfloat16_as_short(__float2bfloat16(lo.x));
            v[1]=__bfloat16_as_short(__float2bfloat16(lo.y));
            v[2]=__bfloat16_as_short(__float2bfloat16(lo.z));
            v[3]=__bfloat16_as_short(__float2bfloat16(lo.w));
            v[4]=__bfloat16_as_short(__float2bfloat16(hi.x));
            v[5]=__bfloat16_as_short(__float2bfloat16(hi.y));
            v[6]=__bfloat16_as_short(__float2bfloat16(hi.z));
            v[7]=__bfloat16_as_short(__float2bfloat16(hi.w));
            bf[ot] = v;
        }
        acc[0] = __builtin_amdgcn_mfma_f32_16x16x32_bf16(af, bf[0], acc[0], 0, 0, 0);
        acc[1] = __builtin_amdgcn_mfma_f32_16x16x32_bf16(af, bf[1], acc[1], 0, 0, 0);
    }

    #pragma unroll
    for (int r = 0; r < 4; ++r) {
        int row = m0 + 4*lhi + r;
        #pragma unroll
        for (int ot = 0; ot < 2; ++ot) {
            int col = o0 + ot*16 + llo;
            Gvb[(size_t)row*O_DIM + col] = __float2bfloat16(acc[ot][r]);
        }
    }
}

// ---------------------------------------------------------------------------
// Kernel 3: fused alpha + featgemm  [r13 math + geometric cull gate]
// ---------------------------------------------------------------------------
__global__ __launch_bounds__(1024) void alphafeat_kernel(
    const float* __restrict__ psort, const float* __restrict__ csort,
    const float* __restrict__ rb, const float* __restrict__ bg,
    const __hip_bfloat16* __restrict__ Gvb, const float* __restrict__ conv_b,
    float* __restrict__ out)
{
    __shared__ __align__(16) char uni[73728];           // GT region (phase B)
    float (*pg)[8]       = (float(*)[8])uni;            // [0,32768)
    float (*cs)[4]       = (float(*)[4])(uni + 32768);  // [32768,49152)
    float (*colbuf)[64][4] = (float(*)[64][4])(uni + 49152); // [49152,65536)
    float (*Pl)[64]      = (float(*)[64])(uni + 65536); // [65536,69632)
    short (*GT)[GT_PITCH] = (short(*)[GT_PITCH])uni;    // 512*72*2 = 73728

    __shared__ short WT[64][WT_PITCH];                  // 25.6 KB
    __shared__ float rbl[N_G][2];                       // 8 KB cull radii
    __shared__ float Tfl[64];
    __shared__ int   idx_lds[MAXG];
    __shared__ int   cntl_s[16];
    __shared__ int   cnt_tot;

    const int t    = threadIdx.x;
    const int c    = t >> 6;        // wave = chunk
    const int lane = t & 63;
    const int tile = blockIdx.x;
    const int hrow = tile >> 1;
    const int w0   = (tile & 1) * 64;

    {
        float4* pgv = reinterpret_cast<float4*>(&pg[0][0]);
        const float4* ps4 = reinterpret_cast<const float4*>(psort);
        pgv[t]        = ps4[t];
        pgv[t + 1024] = ps4[t + 1024];
        float4* csv = reinterpret_cast<float4*>(&cs[0][0]);
        csv[t] = reinterpret_cast<const float4*>(csort)[t];
        reinterpret_cast<float2*>(&rbl[0][0])[t] =
            reinterpret_cast<const float2*>(rb)[t];
        int* wtz = (int*)&WT[0][0];
        for (int i = t; i < 64*WT_PITCH/2; i += 1024) wtz[i] = 0;
        if (t < MAXG) idx_lds[t] = 0;
    }
    __syncthreads();

    const float gx = (float)(w0 + lane);
    const float gy = (float)hrow;
    const float wlo = (float)w0;
    const float whi = (float)(w0 + 63);

    // ---- pass 1: per-chunk transmittance + survivor count (culled) ----
    float pref = 1.f;
    int cnt = 0;
    for (int j = 0; j < 64; ++j) {
        int g = c*64 + j;
        float2 R = *reinterpret_cast<const float2*>(&rbl[g][0]);
        float4 A = *reinterpret_cast<const float4*>(&pg[g][0]);
        bool hit = (R.x >= 0.f) && (fabsf(A.y - gy) <= R.y)
                && (A.x >= wlo - R.x) && (A.x <= whi + R.x);
        if (hit) {
            float4 B = *reinterpret_cast<const float4*>(&pg[g][4]);
            float dx = A.x - gx, dy = A.y - gy;
            float pw = -0.5f*(A.z*dx*dx + B.x*dy*dy) - A.w*dx*dy;
            float al = fminf(0.99f, B.y*__expf(pw));
            bool keep = (pw <= 0.f) && (al >= (1.f/255.f)) && (B.w > 0.5f);
            float a = keep ? al : 0.f;
            float w = pref * a;
            pref *= 1.f - a;
            cnt += (__ballot(w > 1e-12f) != 0ull) ? 1 : 0;
        }
    }
    Pl[c][lane] = pref;
    if (lane == 0) cntl_s[c] = cnt;
    __syncthreads();

    int base = 0;
    float cp = 1.f;
    for (int cc = 0; cc < c; ++cc) {
        base += cntl_s[cc];
        cp *= Pl[cc][lane];
    }
    if (c == 15) {
        Tfl[lane] = cp * Pl[15][lane];
        if (lane == 0) {
            int tot = base + cntl_s[15];
            cnt_tot = (tot < MAXG) ? tot : MAXG;
        }
    }

    // ---- pass 2: weights -> WT LDS, color accum (culled) ----
    float pref2 = 1.f;
    int slot = base;
    float col0 = 0.f, col1 = 0.f, col2 = 0.f;
    for (int j = 0; j < 64; ++j) {
        int g = c*64 + j;
        float2 R = *reinterpret_cast<const float2*>(&rbl[g][0]);
        float4 A = *reinterpret_cast<const float4*>(&pg[g][0]);
        bool hit = (R.x >= 0.f) && (fabsf(A.y - gy) <= R.y)
                && (A.x >= wlo - R.x) && (A.x <= whi + R.x);
        if (hit) {
            float4 B = *reinterpret_cast<const float4*>(&pg[g][4]);
            float dx = A.x - gx, dy = A.y - gy;
            float pw = -0.5f*(A.z*dx*dx + B.x*dy*dy) - A.w*dx*dy;
            float al = fminf(0.99f, B.y*__expf(pw));
            bool keep = (pw <= 0.f) && (al >= (1.f/255.f)) && (B.w > 0.5f);
            float a = keep ? al : 0.f;
            float w = pref2 * a;
            pref2 *= 1.f - a;
            if (__ballot(w > 1e-12f) != 0ull) {
                float wfin = w * cp;
                if (slot < MAXG) {
                    WT[lane][slot] = __bfloat16_as_short(__float2bfloat16(wfin));
                    if (lane == 0) idx_lds[slot] = g;
                }
                float4 cv = *reinterpret_cast<const float4*>(&cs[g][0]);
                col0 += wfin*cv.x; col1 += wfin*cv.y; col2 += wfin*cv.z;
                ++slot;
            }
        }
    }

    colbuf[c][lane][0] = col0; colbuf[c][lane][1] = col1; colbuf[c][lane][2] = col2;
    __syncthreads();

    if (t < 64) {
        float r = 0.f, g = 0.f, b = 0.f;
        #pragma unroll
        for (int k = 0; k < 16; ++k) {
            r += colbuf[k][t][0]; g += colbuf[k][t][1]; b += colbuf[k][t][2];
        }
        float Tf = Tfl[t];
        int pix = hrow*W_IMG + w0 + t;
        out[0*PIX + pix] = r + Tf*bg[0];
        out[1*PIX + pix] = g + Tf*bg[1];
        out[2*PIX + pix] = b + Tf*bg[2];
    }
    __syncthreads();    // colbuf/pg/cs dead; WT/idx/cnt_tot visible

    // ---- featgemm phase: 16 waves x 32 o ----
    int scnt = cnt_tot;
    scnt = (scnt < 0) ? 0 : ((scnt > MAXG) ? MAXG : scnt);
    const short* gvs = (const short*)Gvb;

    f32x4 acc[2][4];
    #pragma unroll
    for (int i = 0; i < 2; ++i)
        #pragma unroll
        for (int j = 0; j < 4; ++j)
            acc[i][j] = (f32x4){0.f,0.f,0.f,0.f};

    const int nchunk = (scnt + 63) >> 6;
    for (int cc = 0; cc < nchunk; ++cc) {
        const int kbase = cc*64;
        {
            const int o = t & 511;
            const int half = t >> 9;
            #pragma unroll
            for (int b = 0; b < 4; ++b) {
                bf16x8 s;
                #pragma unroll
                for (int j = 0; j < 8; ++j) {
                    int k = kbase + half*32 + b*8 + j;
                    s[j] = (k < scnt) ? gvs[(size_t)idx_lds[k]*O_DIM + o] : (short)0;
                }
                *(bf16x8*)&GT[o][half*32 + b*8] = s;
            }
        }
        __syncthreads();

        #pragma unroll
        for (int ks = 0; ks < 2; ++ks) {
            const int kf = 8*(lane>>4);
            bf16x8 bfr[4];
            #pragma unroll
            for (int pt = 0; pt < 4; ++pt)
                bfr[pt] = *(const bf16x8*)&WT[pt*16 + (lane&15)][kbase + ks*32 + kf];
            #pragma unroll
            for (int ot = 0; ot < 2; ++ot) {
                bf16x8 af = *(const bf16x8*)&GT[c*32 + ot*16 + (lane&15)][ks*32 + kf];
                #pragma unroll
                for (int pt = 0; pt < 4; ++pt)
                    acc[ot][pt] = __builtin_amdgcn_mfma_f32_16x16x32_bf16(
                        af, bfr[pt], acc[ot][pt], 0, 0, 0);
            }
        }
        __syncthreads();
    }

    const int pixbase = hrow*W_IMG + w0;
    #pragma unroll
    for (int ot = 0; ot < 2; ++ot) {
        #pragma unroll
        for (int r = 0; r < 4; ++r) {
            int o = c*32 + ot*16 + 4*(lane>>4) + r;
            float cb = conv_b[o];
            #pragma unroll
            for (int pt = 0; pt < 4; ++pt) {
                out[FEAT_OFF + (size_t)o*PIX + pixbase + pt*16 + (lane&15)]
                    = acc[ot][pt][r] + cb;
            }
        }
    }
}

// ---------------------------------------------------------------------------
extern "C" void kernel_launch(void* const* d_in, const int* in_sizes, int n_in,
                              void* d_out, int out_size, void* d_ws, size_t ws_size,
                              hipStream_t stream)
{
    const float* means  = (const float*)d_in[0];
    const float* opac   = (const float*)d_in[2];
    const float* colors = (const float*)d_in[3];
    const float* sem    = (const float*)d_in[4];
    const float* scales = (const float*)d_in[5];
    const float* rots   = (const float*)d_in[6];
    const float* view   = (const float*)d_in[7];
    const float* proj   = (const float*)d_in[8];
    const float* bg     = (const float*)d_in[9];
    const float* conv_w = (const float*)d_in[11];
    const float* conv_b = (const float*)d_in[12];
    float* out = (float*)d_out;

    // --- workspace layout (f32 slots; sizes audited in BYTES) ---
    // psort: [0, 8192)        1024*8 f32
    // csort: [8192, 12288)    1024*4 f32
    // order: [12288, 13312)   1024 int
    // rb:    [13312, 15360)   1024*2 f32
    // Gvb:   [16384, 278528)  1024*512 bf16 = 1,048,576 B = 262,144 f32 slots
    float* wsf   = (float*)d_ws;
    float* psort = wsf;
    float* csort = wsf + 8192;
    int*   order = (int*)(wsf + 12288);
    float* rb    = wsf + 13312;
    __hip_bfloat16* Gvb = (__hip_bfloat16*)(wsf + 16384);

    float* radii_out = out + RAD_OFF;

    preprank_kernel<<<4, 256, 0, stream>>>(means, opac, colors, scales, rots,
                                           view, proj, order, psort, csort,
                                           rb, radii_out);
    gemmG_kernel<<<dim3(16,16), 256, 0, stream>>>(sem, conv_w, order, Gvb);
    alphafeat_kernel<<<256, 1024, 0, stream>>>(psort, csort, rb, bg, Gvb,
                                               conv_b, out);
}

// Round 16
// 69.145 us; speedup vs baseline: 2.8683x; 1.2982x over previous
//
#include <hip/hip_runtime.h>
#include <hip/hip_bf16.h>
#include <math.h>

#define H_IMG 128
#define W_IMG 128
#define N_G   1024
#define F_DIM 512
#define O_DIM 512
#define PIX   (H_IMG*W_IMG)        // 16384
#define FEAT_OFF 49152             // 3*PIX
#define RAD_OFF  (49152 + 512*16384)
#define MAXG  192                  // per-tile survivor cap (validated r2-r15)
#define WT_PITCH 200               // shorts; 400B row stride (16B-aligned)
#define GT_PITCH 72                // shorts; 144B row stride (16B-aligned)

typedef __attribute__((ext_vector_type(8))) short bf16x8;
typedef __attribute__((ext_vector_type(4))) float f32x4;

// ---------------------------------------------------------------------------
// Kernel 1: fused prep + rank + pack + cull-radius emit.
// 16 blocks x 256 thr: rank of 64 n's per block, m-loop split 4-way.
// ---------------------------------------------------------------------------
__global__ __launch_bounds__(256) void preprank_kernel(
    const float* __restrict__ means,
    const float* __restrict__ opac,
    const float* __restrict__ colors,
    const float* __restrict__ scales,
    const float* __restrict__ rots,
    const float* __restrict__ view,
    const float* __restrict__ proj,
    int* __restrict__ order,
    float* __restrict__ psort,
    float* __restrict__ csort,
    float* __restrict__ rb,
    float* __restrict__ radii_out)
{
    __shared__ float d[N_G];
    __shared__ int pr[64][4];
    const int t = threadIdx.x;
    const float v2 = view[2], v6 = view[6], v10 = view[10], v14 = view[14];
    for (int i = t; i < N_G; i += 256)
        d[i] = means[3*i]*v2 + means[3*i+1]*v6 + means[3*i+2]*v10 + v14;
    __syncthreads();

    const int ln = t & 63;              // local n
    const int ch = t >> 6;              // m-chunk
    const int n  = blockIdx.x*64 + ln;
    const float depth = d[n];

    {
        int rp = 0;
        const int mbeg = ch*256;
        for (int m = mbeg; m < mbeg + 256; ++m) {
            float dm = d[m];
            rp += (dm < depth) || (dm == depth && m < n);
        }
        pr[ln][ch] = rp;
    }
    __syncthreads();
    if (ch != 0) return;

    const int r = pr[ln][0] + pr[ln][1] + pr[ln][2] + pr[ln][3];

    float x = means[3*n], y = means[3*n+1], z = means[3*n+2];
    float pv0 = x*view[0] + y*view[4] + z*view[8]  + view[12];
    float pv1 = x*view[1] + y*view[5] + z*view[9]  + view[13];
    float ph0 = x*proj[0] + y*proj[4] + z*proj[8]  + proj[12];
    float ph1 = x*proj[1] + y*proj[5] + z*proj[9]  + proj[13];
    float phw = x*proj[3] + y*proj[7] + z*proj[11] + proj[15];
    float denom = phw + 1e-7f;
    float pp0 = ph0/denom, pp1 = ph1/denom;

    float qr=rots[4*n], qx=rots[4*n+1], qy=rots[4*n+2], qz=rots[4*n+3];
    float qn = sqrtf(qr*qr+qx*qx+qy*qy+qz*qz);
    qr/=qn; qx/=qn; qy/=qn; qz/=qn;
    float R00=1.f-2.f*(qy*qy+qz*qz), R01=2.f*(qx*qy-qr*qz), R02=2.f*(qx*qz+qr*qy);
    float R10=2.f*(qx*qy+qr*qz), R11=1.f-2.f*(qx*qx+qz*qz), R12=2.f*(qy*qz-qr*qx);
    float R20=2.f*(qx*qz-qr*qy), R21=2.f*(qy*qz+qr*qx), R22=1.f-2.f*(qx*qx+qy*qy);
    float s0=scales[3*n], s1=scales[3*n+1], s2=scales[3*n+2];
    float M00=R00*s0, M01=R01*s1, M02=R02*s2;
    float M10=R10*s0, M11=R11*s1, M12=R12*s2;
    float M20=R20*s0, M21=R21*s1, M22=R22*s2;
    float c00=M00*M00+M01*M01+M02*M02;
    float c01=M00*M10+M01*M11+M02*M12;
    float c02=M00*M20+M01*M21+M02*M22;
    float c11=M10*M10+M11*M11+M12*M12;
    float c12=M10*M20+M11*M21+M12*M22;
    float c22=M20*M20+M21*M21+M22*M22;

    const float fx=128.f, fy=128.f;
    float tz = depth;
    float txz = fminf(fmaxf(pv0/tz, -0.65f), 0.65f) * tz;
    float tyz = fminf(fmaxf(pv1/tz, -0.65f), 0.65f) * tz;
    float J00 = fx/tz,  J02 = -fx*txz/(tz*tz);
    float J11 = fy/tz,  J12 = -fy*tyz/(tz*tz);
    float T00=J00*view[0] + J02*view[2];
    float T01=J00*view[4] + J02*view[6];
    float T02=J00*view[8] + J02*view[10];
    float T10=J11*view[1] + J12*view[2];
    float T11=J11*view[5] + J12*view[6];
    float T12=J11*view[9] + J12*view[10];
    float u0 = T00*c00 + T01*c01 + T02*c02;
    float u1 = T00*c01 + T01*c11 + T02*c12;
    float u2 = T00*c02 + T01*c12 + T02*c22;
    float v0 = T10*c00 + T11*c01 + T12*c02;
    float v1 = T10*c01 + T11*c11 + T12*c12;
    float v2r= T10*c02 + T11*c12 + T12*c22;
    float a00 = u0*T00 + u1*T01 + u2*T02 + 0.3f;
    float a01 = u0*T10 + u1*T11 + u2*T12;
    float a11 = v0*T10 + v1*T11 + v2r*T12 + 0.3f;

    float det = a00*a11 - a01*a01;
    float dsafe = (det==0.f) ? 1.f : det;
    float inv = 1.f/dsafe;
    float con0 =  a11*inv, con1 = -a01*inv, con2 = a00*inv;
    float mid = 0.5f*(a00+a11);
    float lam1 = mid + sqrtf(fmaxf(0.1f, mid*mid - det));
    int irad = (int)ceilf(3.f*sqrtf(lam1));
    float pxc = ((pp0+1.f)*128.f - 1.f)*0.5f;
    float pyc = ((pp1+1.f)*128.f - 1.f)*0.5f;
    bool valid = (depth > 0.2f) && (det != 0.f);

    radii_out[n] = valid ? (float)irad : 0.f;
    order[r] = n;
    float* p = psort + 8*r;
    p[0]=pxc; p[1]=pyc; p[2]=con0; p[3]=con1; p[4]=con2;
    p[5]=opac[n]; p[6]=depth; p[7]= valid ? 1.f : 0.f;
    csort[4*r+0] = colors[3*n+0];
    csort[4*r+1] = colors[3*n+1];
    csort[4*r+2] = colors[3*n+2];
    csort[4*r+3] = 0.f;

    float op = opac[n];
    float tau = logf(255.f * op);
    bool active = valid && (tau > 0.f);
    float rx = active ? (sqrtf(2.f*tau*a00) + 0.01f) : -1.f;
    float ry = active ? (sqrtf(2.f*tau*a11) + 0.01f) : -1.f;
    rb[2*r+0] = rx;
    rb[2*r+1] = ry;
}

// ---------------------------------------------------------------------------
// Kernel 2: G[m][o] via MFMA, direct-from-global, depth-2 software pipeline.
// grid (32 o-tiles of 16, 16 m-tiles of 64) = 512 blocks x 4 waves;
// each wave: 16m x 16o, full K. 2 blocks/CU -> 2 waves/SIMD.
// ---------------------------------------------------------------------------
__global__ __launch_bounds__(256) void gemmG_kernel(const float* __restrict__ S,
                                                    const float* __restrict__ Wm,
                                                    const int* __restrict__ order,
                                                    __hip_bfloat16* __restrict__ Gvb)
{
    const int t    = threadIdx.x;
    const int lane = t & 63;
    const int wv   = t >> 6;
    const int m0   = blockIdx.y * 64 + wv * 16;
    const int o0   = blockIdx.x * 16;
    const int lhi  = lane >> 4;
    const int llo  = lane & 15;

    const int arow = order[m0 + llo] & (N_G - 1);
    const float* Ar = S  + (size_t)arow*F_DIM + 8*lhi;
    const float* Br = Wm + (size_t)(o0 + llo)*F_DIM + 8*lhi;

    f32x4 acc = (f32x4){0.f,0.f,0.f,0.f};

    float4 a0 = *reinterpret_cast<const float4*>(Ar);
    float4 a1 = *reinterpret_cast<const float4*>(Ar + 4);
    float4 b0 = *reinterpret_cast<const float4*>(Br);
    float4 b1 = *reinterpret_cast<const float4*>(Br + 4);

    for (int k0 = 0; k0 < F_DIM; k0 += 32) {
        float4 na0, na1, nb0, nb1;
        const bool more = (k0 + 32) < F_DIM;
        if (more) {
            na0 = *reinterpret_cast<const float4*>(Ar + k0 + 32);
            na1 = *reinterpret_cast<const float4*>(Ar + k0 + 36);
            nb0 = *reinterpret_cast<const float4*>(Br + k0 + 32);
            nb1 = *reinterpret_cast<const float4*>(Br + k0 + 36);
        }
        bf16x8 af, bf;
        af[0]=__bfloat16_as_short(__float2bfloat16(a0.x));
        af[1]=__bfloat16_as_short(__float2bfloat16(a0.y));
        af[2]=__bfloat16_as_short(__float2bfloat16(a0.z));
        af[3]=__bfloat16_as_short(__float2bfloat16(a0.w));
        af[4]=__bfloat16_as_short(__float2bfloat16(a1.x));
        af[5]=__bfloat16_as_short(__float2bfloat16(a1.y));
        af[6]=__bfloat16_as_short(__float2bfloat16(a1.z));
        af[7]=__bfloat16_as_short(__float2bfloat16(a1.w));
        bf[0]=__bfloat16_as_short(__float2bfloat16(b0.x));
        bf[1]=__bfloat16_as_short(__float2bfloat16(b0.y));
        bf[2]=__bfloat16_as_short(__float2bfloat16(b0.z));
        bf[3]=__bfloat16_as_short(__float2bfloat16(b0.w));
        bf[4]=__bfloat16_as_short(__float2bfloat16(b1.x));
        bf[5]=__bfloat16_as_short(__float2bfloat16(b1.y));
        bf[6]=__bfloat16_as_short(__float2bfloat16(b1.z));
        bf[7]=__bfloat16_as_short(__float2bfloat16(b1.w));
        acc = __builtin_amdgcn_mfma_f32_16x16x32_bf16(af, bf, acc, 0, 0, 0);
        if (more) { a0 = na0; a1 = na1; b0 = nb0; b1 = nb1; }
    }

    #pragma unroll
    for (int r = 0; r < 4; ++r) {
        int row = m0 + 4*lhi + r;
        Gvb[(size_t)row*O_DIM + o0 + llo] = __float2bfloat16(acc[r]);
    }
}

// ---------------------------------------------------------------------------
// Kernel 3: fused alpha + featgemm  [r15-exact]
// ---------------------------------------------------------------------------
__global__ __launch_bounds__(1024) void alphafeat_kernel(
    const float* __restrict__ psort, const float* __restrict__ csort,
    const float* __restrict__ rb, const float* __restrict__ bg,
    const __hip_bfloat16* __restrict__ Gvb, const float* __restrict__ conv_b,
    float* __restrict__ out)
{
    __shared__ __align__(16) char uni[73728];           // GT region (phase B)
    float (*pg)[8]       = (float(*)[8])uni;            // [0,32768)
    float (*cs)[4]       = (float(*)[4])(uni + 32768);  // [32768,49152)
    float (*colbuf)[64][4] = (float(*)[64][4])(uni + 49152); // [49152,65536)
    float (*Pl)[64]      = (float(*)[64])(uni + 65536); // [65536,69632)
    short (*GT)[GT_PITCH] = (short(*)[GT_PITCH])uni;    // 512*72*2 = 73728

    __shared__ short WT[64][WT_PITCH];                  // 25.6 KB
    __shared__ float rbl[N_G][2];                       // 8 KB cull radii
    __shared__ float Tfl[64];
    __shared__ int   idx_lds[MAXG];
    __shared__ int   cntl_s[16];
    __shared__ int   cnt_tot;

    const int t    = threadIdx.x;
    const int c    = t >> 6;        // wave = chunk
    const int lane = t & 63;
    const int tile = blockIdx.x;
    const int hrow = tile >> 1;
    const int w0   = (tile & 1) * 64;

    {
        float4* pgv = reinterpret_cast<float4*>(&pg[0][0]);
        const float4* ps4 = reinterpret_cast<const float4*>(psort);
        pgv[t]        = ps4[t];
        pgv[t + 1024] = ps4[t + 1024];
        float4* csv = reinterpret_cast<float4*>(&cs[0][0]);
        csv[t] = reinterpret_cast<const float4*>(csort)[t];
        reinterpret_cast<float2*>(&rbl[0][0])[t] =
            reinterpret_cast<const float2*>(rb)[t];
        int* wtz = (int*)&WT[0][0];
        for (int i = t; i < 64*WT_PITCH/2; i += 1024) wtz[i] = 0;
        if (t < MAXG) idx_lds[t] = 0;
    }
    __syncthreads();

    const float gx = (float)(w0 + lane);
    const float gy = (float)hrow;
    const float wlo = (float)w0;
    const float whi = (float)(w0 + 63);

    // ---- pass 1: per-chunk transmittance + survivor count (culled) ----
    float pref = 1.f;
    int cnt = 0;
    for (int j = 0; j < 64; ++j) {
        int g = c*64 + j;
        float2 R = *reinterpret_cast<const float2*>(&rbl[g][0]);
        float4 A = *reinterpret_cast<const float4*>(&pg[g][0]);
        bool hit = (R.x >= 0.f) && (fabsf(A.y - gy) <= R.y)
                && (A.x >= wlo - R.x) && (A.x <= whi + R.x);
        if (hit) {
            float4 B = *reinterpret_cast<const float4*>(&pg[g][4]);
            float dx = A.x - gx, dy = A.y - gy;
            float pw = -0.5f*(A.z*dx*dx + B.x*dy*dy) - A.w*dx*dy;
            float al = fminf(0.99f, B.y*__expf(pw));
            bool keep = (pw <= 0.f) && (al >= (1.f/255.f)) && (B.w > 0.5f);
            float a = keep ? al : 0.f;
            float w = pref * a;
            pref *= 1.f - a;
            cnt += (__ballot(w > 1e-12f) != 0ull) ? 1 : 0;
        }
    }
    Pl[c][lane] = pref;
    if (lane == 0) cntl_s[c] = cnt;
    __syncthreads();

    int base = 0;
    float cp = 1.f;
    for (int cc = 0; cc < c; ++cc) {
        base += cntl_s[cc];
        cp *= Pl[cc][lane];
    }
    if (c == 15) {
        Tfl[lane] = cp * Pl[15][lane];
        if (lane == 0) {
            int tot = base + cntl_s[15];
            cnt_tot = (tot < MAXG) ? tot : MAXG;
        }
    }

    // ---- pass 2: weights -> WT LDS, color accum (culled) ----
    float pref2 = 1.f;
    int slot = base;
    float col0 = 0.f, col1 = 0.f, col2 = 0.f;
    for (int j = 0; j < 64; ++j) {
        int g = c*64 + j;
        float2 R = *reinterpret_cast<const float2*>(&rbl[g][0]);
        float4 A = *reinterpret_cast<const float4*>(&pg[g][0]);
        bool hit = (R.x >= 0.f) && (fabsf(A.y - gy) <= R.y)
                && (A.x >= wlo - R.x) && (A.x <= whi + R.x);
        if (hit) {
            float4 B = *reinterpret_cast<const float4*>(&pg[g][4]);
            float dx = A.x - gx, dy = A.y - gy;
            float pw = -0.5f*(A.z*dx*dx + B.x*dy*dy) - A.w*dx*dy;
            float al = fminf(0.99f, B.y*__expf(pw));
            bool keep = (pw <= 0.f) && (al >= (1.f/255.f)) && (B.w > 0.5f);
            float a = keep ? al : 0.f;
            float w = pref2 * a;
            pref2 *= 1.f - a;
            if (__ballot(w > 1e-12f) != 0ull) {
                float wfin = w * cp;
                if (slot < MAXG) {
                    WT[lane][slot] = __bfloat16_as_short(__float2bfloat16(wfin));
                    if (lane == 0) idx_lds[slot] = g;
                }
                float4 cv = *reinterpret_cast<const float4*>(&cs[g][0]);
                col0 += wfin*cv.x; col1 += wfin*cv.y; col2 += wfin*cv.z;
                ++slot;
            }
        }
    }

    colbuf[c][lane][0] = col0; colbuf[c][lane][1] = col1; colbuf[c][lane][2] = col2;
    __syncthreads();

    if (t < 64) {
        float r = 0.f, g = 0.f, b = 0.f;
        #pragma unroll
        for (int k = 0; k < 16; ++k) {
            r += colbuf[k][t][0]; g += colbuf[k][t][1]; b += colbuf[k][t][2];
        }
        float Tf = Tfl[t];
        int pix = hrow*W_IMG + w0 + t;
        out[0*PIX + pix] = r + Tf*bg[0];
        out[1*PIX + pix] = g + Tf*bg[1];
        out[2*PIX + pix] = b + Tf*bg[2];
    }
    __syncthreads();    // colbuf/pg/cs dead; WT/idx/cnt_tot visible

    // ---- featgemm phase: 16 waves x 32 o ----
    int scnt = cnt_tot;
    scnt = (scnt < 0) ? 0 : ((scnt > MAXG) ? MAXG : scnt);
    const short* gvs = (const short*)Gvb;

    f32x4 acc[2][4];
    #pragma unroll
    for (int i = 0; i < 2; ++i)
        #pragma unroll
        for (int j = 0; j < 4; ++j)
            acc[i][j] = (f32x4){0.f,0.f,0.f,0.f};

    const int nchunk = (scnt + 63) >> 6;
    for (int cc = 0; cc < nchunk; ++cc) {
        const int kbase = cc*64;
        {
            const int o = t & 511;
            const int half = t >> 9;
            #pragma unroll
            for (int b = 0; b < 4; ++b) {
                bf16x8 s;
                #pragma unroll
                for (int j = 0; j < 8; ++j) {
                    int k = kbase + half*32 + b*8 + j;
                    s[j] = (k < scnt) ? gvs[(size_t)idx_lds[k]*O_DIM + o] : (short)0;
                }
                *(bf16x8*)&GT[o][half*32 + b*8] = s;
            }
        }
        __syncthreads();

        #pragma unroll
        for (int ks = 0; ks < 2; ++ks) {
            const int kf = 8*(lane>>4);
            bf16x8 bfr[4];
            #pragma unroll
            for (int pt = 0; pt < 4; ++pt)
                bfr[pt] = *(const bf16x8*)&WT[pt*16 + (lane&15)][kbase + ks*32 + kf];
            #pragma unroll
            for (int ot = 0; ot < 2; ++ot) {
                bf16x8 af = *(const bf16x8*)&GT[c*32 + ot*16 + (lane&15)][ks*32 + kf];
                #pragma unroll
                for (int pt = 0; pt < 4; ++pt)
                    acc[ot][pt] = __builtin_amdgcn_mfma_f32_16x16x32_bf16(
                        af, bfr[pt], acc[ot][pt], 0, 0, 0);
            }
        }
        __syncthreads();
    }

    const int pixbase = hrow*W_IMG + w0;
    #pragma unroll
    for (int ot = 0; ot < 2; ++ot) {
        #pragma unroll
        for (int r = 0; r < 4; ++r) {
            int o = c*32 + ot*16 + 4*(lane>>4) + r;
            float cb = conv_b[o];
            #pragma unroll
            for (int pt = 0; pt < 4; ++pt) {
                out[FEAT_OFF + (size_t)o*PIX + pixbase + pt*16 + (lane&15)]
                    = acc[ot][pt][r] + cb;
            }
        }
    }
}

// ---------------------------------------------------------------------------
extern "C" void kernel_launch(void* const* d_in, const int* in_sizes, int n_in,
                              void* d_out, int out_size, void* d_ws, size_t ws_size,
                              hipStream_t stream)
{
    const float* means  = (const float*)d_in[0];
    const float* opac   = (const float*)d_in[2];
    const float* colors = (const float*)d_in[3];
    const float* sem    = (const float*)d_in[4];
    const float* scales = (const float*)d_in[5];
    const float* rots   = (const float*)d_in[6];
    const float* view   = (const float*)d_in[7];
    const float* proj   = (const float*)d_in[8];
    const float* bg     = (const float*)d_in[9];
    const float* conv_w = (const float*)d_in[11];
    const float* conv_b = (const float*)d_in[12];
    float* out = (float*)d_out;

    // --- workspace layout (f32 slots; sizes audited in BYTES) ---
    // psort: [0, 8192)        1024*8 f32
    // csort: [8192, 12288)    1024*4 f32
    // order: [12288, 13312)   1024 int
    // rb:    [13312, 15360)   1024*2 f32
    // Gvb:   [16384, 278528)  1024*512 bf16 = 1,048,576 B = 262,144 f32 slots
    float* wsf   = (float*)d_ws;
    float* psort = wsf;
    float* csort = wsf + 8192;
    int*   order = (int*)(wsf + 12288);
    float* rb    = wsf + 13312;
    __hip_bfloat16* Gvb = (__hip_bfloat16*)(wsf + 16384);

    float* radii_out = out + RAD_OFF;

    preprank_kernel<<<16, 256, 0, stream>>>(means, opac, colors, scales, rots,
                                            view, proj, order, psort, csort,
                                            rb, radii_out);
    gemmG_kernel<<<dim3(32,16), 256, 0, stream>>>(sem, conv_w, order, Gvb);
    alphafeat_kernel<<<256, 1024, 0, stream>>>(psort, csort, rb, bg, Gvb,
                                               conv_b, out);
}